// Round 1
// 1046.328 us; speedup vs baseline: 1.2127x; 1.2127x over previous
//
#include <hip/hip_runtime.h>
#include <hip/hip_bf16.h>

using bf16 = __hip_bfloat16;
typedef __attribute__((ext_vector_type(8))) short short8;
typedef __attribute__((ext_vector_type(4))) float floatx4;

__device__ __forceinline__ float b2f(bf16 x) { return __bfloat162float(x); }
__device__ __forceinline__ bf16  f2b(float x) { return __float2bfloat16(x); }
__device__ __forceinline__ float u2f(unsigned x) { return __uint_as_float(x); }
// dual-dtype raw-input load: fp32 or bf16 depending on runtime flag
__device__ __forceinline__ float ld(const void* p, size_t i, int f32) {
  return f32 ? ((const float*)p)[i] : b2f(((const bf16*)p)[i]);
}

// ---------------- dtype detector ----------------
__global__ void detect_kernel(const void* q, int* flag) {
  if (threadIdx.x == 0) {
    const unsigned short* u = (const unsigned short*)q;
    int f = 0;
    for (int i = 0; i < 128; i++) {
      unsigned e = (u[i] >> 7) & 0xFF;
      if (e >= 141) f = 1;
    }
    *flag = f;
  }
}

// ---------------- feat transpose: (6,128,h,w) -> (6,h,w,128) ----------------
__global__ __launch_bounds__(256) void tfeat_kernel(const void* __restrict__ in,
                                                    bf16* __restrict__ out, int h, int w,
                                                    const int* flag) {
  int f = *flag;
  int idx = blockIdx.x * 256 + threadIdx.x;
  int c = idx & 127;
  int rest = idx >> 7;
  int x = rest % w;
  int rest2 = rest / w;
  int y = rest2 % h;
  int n = rest2 / h;
  out[idx] = f2b(ld(in, (size_t)((n * 128 + c) * h + y) * w + x, f));
}

// ---------------- weight transpose: [K,N] -> [N,K] ----------------
__global__ __launch_bounds__(256) void tw_kernel(const void* __restrict__ in,
                                                 bf16* __restrict__ out, int K, int N,
                                                 const int* flag) {
  int f = *flag;
  int idx = blockIdx.x * 256 + threadIdx.x;
  if (idx >= K * N) return;
  int n = idx % N, k = idx / N;
  out[n * K + k] = f2b(ld(in, idx, f));
}

// ---------------- S1: logits+softmax+projection, one thread per (q,p) row ----------------
__global__ __launch_bounds__(256) void logit_proj_kernel(
    const void* __restrict__ query,      // [320000,128] raw
    const void* __restrict__ query_pos,  // [8,40000,3] raw
    const void* __restrict__ l2i,        // [6,4,4] raw
    const void* __restrict__ W_sw,       // [128,16] raw
    const void* __restrict__ b_sw,       // [16] raw
    float* __restrict__ swG,             // [320000,16]
    float* __restrict__ uG, float* __restrict__ vG, int* __restrict__ cvG,
    const int* flag) {
  const int f32 = *flag;
  const int t = threadIdx.x;
  const int row0 = blockIdx.x * 256;
  __shared__ float As[256][33];
  __shared__ float wswS[2048];
  __shared__ float bswS[16];
  for (int i = t; i < 2048; i += 256) wswS[i] = ld(W_sw, i, f32);
  if (t < 16) bswS[t] = ld(b_sw, t, f32);
  float acc[16];
  #pragma unroll
  for (int c = 0; c < 16; c++) acc[c] = 0.f;
  for (int k0 = 0; k0 < 128; k0 += 32) {
    __syncthreads();
    for (int i = t; i < 8192; i += 256) {
      int r = i >> 5, kk = i & 31;
      As[r][kk] = ld(query, (size_t)(row0 + r) * 128 + k0 + kk, f32);
    }
    __syncthreads();
    for (int kk = 0; kk < 32; kk++) {
      float a = As[t][kk];
      #pragma unroll
      for (int c = 0; c < 16; c++) acc[c] += a * wswS[(k0 + kk) * 16 + c];
    }
  }
  const int row = row0 + t;
  #pragma unroll
  for (int c = 0; c < 16; c++) acc[c] += bswS[c];
  #pragma unroll
  for (int g = 0; g < 4; g++) {
    float a0 = acc[4 * g], a1 = acc[4 * g + 1], a2 = acc[4 * g + 2], a3 = acc[4 * g + 3];
    float mx = fmaxf(fmaxf(a0, a1), fmaxf(a2, a3));
    float e0 = expf(a0 - mx), e1 = expf(a1 - mx), e2 = expf(a2 - mx), e3 = expf(a3 - mx);
    float inv = 1.f / (e0 + e1 + e2 + e3);
    swG[(size_t)row * 16 + 4 * g]     = e0 * inv;
    swG[(size_t)row * 16 + 4 * g + 1] = e1 * inv;
    swG[(size_t)row * 16 + 4 * g + 2] = e2 * inv;
    swG[(size_t)row * 16 + 4 * g + 3] = e3 * inv;
  }
  // projection
  int q = row >> 3, p = row & 7;
  float q0 = ld(query_pos, ((size_t)p * 40000 + q) * 3 + 0, f32);
  float q1 = ld(query_pos, ((size_t)p * 40000 + q) * 3 + 1, f32);
  float q2 = ld(query_pos, ((size_t)p * 40000 + q) * 3 + 2, f32);
  float px = q0 * 100.f - 50.f;
  float py = q1 * 100.f - 50.f;
  float pz = q2 * 8.f - 4.f;
  int cam = 0, found = 0;
  float usel = 0.f, vsel = 0.f;
  for (int n = 0; n < 6; n++) {
    float m[12];
    #pragma unroll
    for (int i = 0; i < 12; i++) m[i] = ld(l2i, n * 16 + i, f32);
    float c0 = m[0] * px + m[1] * py + m[2] * pz + m[3];
    float c1 = m[4] * px + m[5] * py + m[6] * pz + m[7];
    float c2 = m[8] * px + m[9] * py + m[10] * pz + m[11];
    float d = fmaxf(c2, 1e-6f);
    float u = (c0 / d) / 480.f;
    float v = (c1 / d) / 224.f;
    int valid = (c2 > 1e-6f) && (u > 0.f) && (u < 1.f) && (v > 0.f) && (v < 1.f);
    if (valid && !found) { found = 1; cam = n; usel = u; vsel = v; }
  }
  uG[row] = usel; vG[row] = vsel; cvG[row] = cam | (found << 3);
}

// ---------------- S2: gather, one wave per (q,p) row; lane owns 2 channels ----------------
__global__ __launch_bounds__(256) void gather_kernel(
    const float* __restrict__ swG, const float* __restrict__ uG,
    const float* __restrict__ vG, const int* __restrict__ cvG,
    const bf16* __restrict__ ft, bf16* __restrict__ X) {
  const int t = threadIdx.x;
  const int lane = t & 63;
  const int row = blockIdx.x * 4 + (t >> 6);
  const unsigned* ftU = (const unsigned*)ft;
  unsigned* XU = (unsigned*)X;
  float acc0 = 0.f, acc1 = 0.f;
  int cv = cvG[row];
  if (cv & 8) {
    float u = uG[row], v = vG[row];
    int cam = cv & 7;
    int g = lane >> 4;
    float wl[4];
    #pragma unroll
    for (int l = 0; l < 4; l++) wl[l] = swG[(size_t)row * 16 + g * 4 + l];
    const int LH[4] = {56, 28, 14, 7}, LW[4] = {120, 60, 30, 15};
    const int FOFFU[4] = {0, 2580480, 3225600, 3386880};  // uint-elem offsets
    #pragma unroll
    for (int l = 0; l < 4; l++) {
      int h = LH[l], w = LW[l];
      int base_l = FOFFU[l] + cam * h * w * 64;
      float x = u * w - 0.5f, y = v * h - 0.5f;
      float x0f = floorf(x), y0f = floorf(y);
      float wx = x - x0f, wy = y - y0f;
      int x0 = (int)x0f, y0 = (int)y0f;
      bool xi0 = (x0 >= 0) && (x0 < w), xi1 = (x0 + 1 >= 0) && (x0 + 1 < w);
      bool yi0 = (y0 >= 0) && (y0 < h), yi1 = (y0 + 1 >= 0) && (y0 + 1 < h);
      float b0 = 0.f, b1 = 0.f;
      if (yi0 && xi0) {
        unsigned vv = ftU[base_l + (y0 * w + x0) * 64 + lane];
        float cw = (1.f - wx) * (1.f - wy);
        b0 += u2f(vv << 16) * cw; b1 += u2f(vv & 0xFFFF0000u) * cw;
      }
      if (yi0 && xi1) {
        unsigned vv = ftU[base_l + (y0 * w + x0 + 1) * 64 + lane];
        float cw = wx * (1.f - wy);
        b0 += u2f(vv << 16) * cw; b1 += u2f(vv & 0xFFFF0000u) * cw;
      }
      if (yi1 && xi0) {
        unsigned vv = ftU[base_l + ((y0 + 1) * w + x0) * 64 + lane];
        float cw = (1.f - wx) * wy;
        b0 += u2f(vv << 16) * cw; b1 += u2f(vv & 0xFFFF0000u) * cw;
      }
      if (yi1 && xi1) {
        unsigned vv = ftU[base_l + ((y0 + 1) * w + x0 + 1) * 64 + lane];
        float cw = wx * wy;
        b0 += u2f(vv << 16) * cw; b1 += u2f(vv & 0xFFFF0000u) * cw;
      }
      acc0 += wl[l] * b0; acc1 += wl[l] * b1;
    }
  }
  unsigned lo = (unsigned)(unsigned short)__bfloat16_as_ushort(f2b(acc0));
  unsigned hi = (unsigned)(unsigned short)__bfloat16_as_ushort(f2b(acc1));
  XU[(size_t)row * 64 + lane] = lo | (hi << 16);
}

// ---------------- bf16 MFMA GEMM: C = relu?(A[M,K] @ Bt[N,K]^T + bias) ----------------
__global__ __launch_bounds__(256) void gemm_bt(
    const bf16* __restrict__ A, const bf16* __restrict__ Bt, const void* __restrict__ bias,
    bf16* __restrict__ Cd, float* __restrict__ Cf,
    int M, int N, int K, int relu, int trans_out, const int* flag) {
  __shared__ bf16 As[64 * 40];
  __shared__ bf16 Bs[64 * 40];
  const int f32 = *flag;
  const int t = threadIdx.x;
  const int bm = blockIdx.x * 64;
  const int bn = blockIdx.y * 64;
  const int wv = t >> 6, lane = t & 63;
  const int wm = (wv >> 1) * 32, wn = (wv & 1) * 32;
  const int quad = lane >> 4, l15 = lane & 15;
  const int srow = t >> 2, scol = (t & 3) * 8;
  floatx4 acc[2][2] = {};
  for (int k0 = 0; k0 < K; k0 += 32) {
    *(uint4*)(&As[srow * 40 + scol]) = *(const uint4*)(&A[(size_t)(bm + srow) * K + k0 + scol]);
    *(uint4*)(&Bs[srow * 40 + scol]) = *(const uint4*)(&Bt[(size_t)(bn + srow) * K + k0 + scol]);
    __syncthreads();
    short8 af[2], bfr[2];
    af[0]  = *(const short8*)(&As[(wm + l15) * 40 + quad * 8]);
    af[1]  = *(const short8*)(&As[(wm + 16 + l15) * 40 + quad * 8]);
    bfr[0] = *(const short8*)(&Bs[(wn + l15) * 40 + quad * 8]);
    bfr[1] = *(const short8*)(&Bs[(wn + 16 + l15) * 40 + quad * 8]);
    #pragma unroll
    for (int mi = 0; mi < 2; mi++)
      #pragma unroll
      for (int ni = 0; ni < 2; ni++)
        acc[mi][ni] = __builtin_amdgcn_mfma_f32_16x16x32_bf16(af[mi], bfr[ni], acc[mi][ni], 0, 0, 0);
    __syncthreads();
  }
  #pragma unroll
  for (int mi = 0; mi < 2; mi++)
    #pragma unroll
    for (int ni = 0; ni < 2; ni++) {
      int gn = bn + wn + ni * 16 + l15;
      float bv = ld(bias, gn, f32);
      #pragma unroll
      for (int r = 0; r < 4; r++) {
        int gm = bm + wm + mi * 16 + quad * 4 + r;
        float v = acc[mi][ni][r] + bv;
        if (relu) v = fmaxf(v, 0.f);
        if (trans_out) Cf[(size_t)gn * M + gm] = v;
        else           Cd[(size_t)gm * N + gn] = f2b(v);
      }
    }
}

// ---------------- pos_emb GEMM: X[q*8+z][e] += MLP(query_pos)[e] ----------------
// One block = 64 rows x full N=128. First-layer weights cached in LDS
// (XOR-swizzled 16B units so the 4 scol-groups hit distinct banks); hidden
// activations built in registers and written with a single ds_write_b128.
__global__ __launch_bounds__(256) void gemm_pe(
    const void* __restrict__ query_pos, const void* __restrict__ pe_w1,
    const void* __restrict__ pe_b1, const void* __restrict__ pe_b2,
    const bf16* __restrict__ pw2t, bf16* __restrict__ X, const int* flag) {
  __shared__ bf16 As[64 * 40];    // hidden tile, 64 rows x 32 k
  __shared__ bf16 Bs[128 * 40];   // pw2t tile, 128 n-rows x 32 k
  __shared__ float w1S[256 * 4];  // [k]{w1_0,w1_1,w1_2,b1}, unit-swizzled
  __shared__ float qpS[64 * 3];
  const int f32 = *flag;
  const int t = threadIdx.x;
  const int bm = blockIdx.x * 64;
  const int wv = t >> 6, lane = t & 63;
  const int wm = (wv & 1) * 32, wn = (wv >> 1) * 64;
  const int quad = lane >> 4, l15 = lane & 15;
  const int srow = t >> 2, scol = (t & 3) * 8;
  // stage w1/b1 once: unit k lives at swizzled unit (k ^ ((k>>3)&7))
  for (int i = t; i < 1024; i += 256) {
    int k = i >> 2, c = i & 3;
    int ku = k ^ ((k >> 3) & 7);
    w1S[ku * 4 + c] = (c < 3) ? ld(pe_w1, c * 256 + k, f32) : ld(pe_b1, k, f32);
  }
  if (t < 64) {
    int r = bm + t, qq = r >> 3, zz = r & 7;
    #pragma unroll
    for (int i = 0; i < 3; i++)
      qpS[t * 3 + i] = ld(query_pos, ((size_t)zz * 40000 + qq) * 3 + i, f32);
  }
  __syncthreads();
  const float a0 = qpS[srow * 3], a1 = qpS[srow * 3 + 1], a2 = qpS[srow * 3 + 2];
  floatx4 acc[2][4] = {};
  for (int k0 = 0; k0 < 256; k0 += 32) {
    // A-tile: 8 hidden activations per thread, one b128 LDS write
    short8 hv;
    #pragma unroll
    for (int j = 0; j < 8; j++) {
      int k = k0 + scol + j;
      int ku = k ^ ((k >> 3) & 7);
      const float* wr = &w1S[ku * 4];
      float h = fmaf(a0, wr[0], fmaf(a1, wr[1], fmaf(a2, wr[2], wr[3])));
      hv[j] = (short)__bfloat16_as_ushort(f2b(fmaxf(h, 0.f)));
    }
    *(short8*)(&As[srow * 40 + scol]) = hv;
    // B-tile: 128 rows x 32 k, two uint4 per thread (each element once/block)
    #pragma unroll
    for (int rep = 0; rep < 2; rep++) {
      int linear = rep * 256 + t;
      int brow = linear >> 2, bcol = (linear & 3) * 8;
      *(uint4*)(&Bs[brow * 40 + bcol]) =
          *(const uint4*)(&pw2t[(size_t)brow * 256 + k0 + bcol]);
    }
    __syncthreads();
    short8 af[2], bfr[4];
    #pragma unroll
    for (int mi = 0; mi < 2; mi++)
      af[mi] = *(const short8*)(&As[(wm + mi * 16 + l15) * 40 + quad * 8]);
    #pragma unroll
    for (int ni = 0; ni < 4; ni++)
      bfr[ni] = *(const short8*)(&Bs[(wn + ni * 16 + l15) * 40 + quad * 8]);
    #pragma unroll
    for (int mi = 0; mi < 2; mi++)
      #pragma unroll
      for (int ni = 0; ni < 4; ni++)
        acc[mi][ni] = __builtin_amdgcn_mfma_f32_16x16x32_bf16(af[mi], bfr[ni], acc[mi][ni], 0, 0, 0);
    __syncthreads();
  }
  #pragma unroll
  for (int mi = 0; mi < 2; mi++)
    #pragma unroll
    for (int ni = 0; ni < 4; ni++) {
      int gn = wn + ni * 16 + l15;
      float bv = ld(pe_b2, gn, f32);
      #pragma unroll
      for (int r = 0; r < 4; r++) {
        int gm = bm + wm + mi * 16 + quad * 4 + r;
        size_t off = (size_t)gm * 128 + gn;
        X[off] = f2b(acc[mi][ni][r] + bv + b2f(X[off]));
      }
    }
}

extern "C" void kernel_launch(void* const* d_in, const int* in_sizes, int n_in,
                              void* d_out, int out_size, void* d_ws, size_t ws_size,
                              hipStream_t stream) {
  int* flag = (int*)d_ws;
  bf16* ws = (bf16*)d_ws;
  bf16* ft   = ws + 5760;                // 6,854,400
  bf16* wt1  = ws + 6860160;             // 512x1024
  bf16* wt2  = ws + 7384448;             // 512x512
  bf16* wt3  = ws + 7646592;             // 512x512
  bf16* wt4  = ws + 7908736;             // 128x512
  bf16* pw2t = ws + 7974272;             // 128x256
  bf16* X    = ws + 8007040;             // 40000x1024
  bf16* Ha   = ws + 48967040;            // 40000x512   (ws total ~139 MB)
  bf16* Hb   = X;                        // alias: X dead after layer-1 GEMM
  // sampling scratch aliased onto Ha (dead until layer-1 GEMM writes it)
  float* swG = (float*)Ha;               // 320000x16 fp32 (10.24M be)
  float* uG  = (float*)(ws + 59207040);  // 320000 fp32
  float* vG  = (float*)(ws + 59847040);  // 320000 fp32
  int*   cvG = (int*)(ws + 60487040);    // 320000 int (ends 61127040 < Ha end)

  detect_kernel<<<1, 64, 0, stream>>>(d_in[4], flag);

  tfeat_kernel<<<20160, 256, 0, stream>>>(d_in[0], ft, 56, 120, flag);
  tfeat_kernel<<<5040, 256, 0, stream>>>(d_in[1], ft + 5160960, 28, 60, flag);
  tfeat_kernel<<<1260, 256, 0, stream>>>(d_in[2], ft + 6451200, 14, 30, flag);
  tfeat_kernel<<<315, 256, 0, stream>>>(d_in[3], ft + 6773760, 7, 15, flag);
  tw_kernel<<<2048, 256, 0, stream>>>(d_in[13], wt1, 1024, 512, flag);
  tw_kernel<<<1024, 256, 0, stream>>>(d_in[15], wt2, 512, 512, flag);
  tw_kernel<<<1024, 256, 0, stream>>>(d_in[17], wt3, 512, 512, flag);
  tw_kernel<<<256, 256, 0, stream>>>(d_in[19], wt4, 512, 128, flag);
  tw_kernel<<<128, 256, 0, stream>>>(d_in[11], pw2t, 256, 128, flag);

  logit_proj_kernel<<<1250, 256, 0, stream>>>(d_in[4], d_in[5], d_in[6], d_in[7], d_in[8],
                                              swG, uG, vG, cvG, flag);
  gather_kernel<<<80000, 256, 0, stream>>>(swG, uG, vG, cvG, ft, X);
  gemm_pe<<<5000, 256, 0, stream>>>(d_in[5], d_in[9], d_in[10], d_in[12],
                                    pw2t, X, flag);

  gemm_bt<<<dim3(625, 8), 256, 0, stream>>>(X,  wt1, d_in[14], Ha, nullptr, 40000, 512, 1024, 1, 0, flag);
  gemm_bt<<<dim3(625, 8), 256, 0, stream>>>(Ha, wt2, d_in[16], Hb, nullptr, 40000, 512, 512, 1, 0, flag);
  gemm_bt<<<dim3(625, 8), 256, 0, stream>>>(Hb, wt3, d_in[18], Ha, nullptr, 40000, 512, 512, 1, 0, flag);
  gemm_bt<<<dim3(625, 2), 256, 0, stream>>>(Ha, wt4, d_in[20], nullptr, (float*)d_out, 40000, 128, 512, 0, 1, flag);
}

// Round 2
// 955.626 us; speedup vs baseline: 1.3278x; 1.0949x over previous
//
#include <hip/hip_runtime.h>
#include <hip/hip_bf16.h>

using bf16 = __hip_bfloat16;
typedef __attribute__((ext_vector_type(8))) short short8;
typedef __attribute__((ext_vector_type(4))) float floatx4;

__device__ __forceinline__ float b2f(bf16 x) { return __bfloat162float(x); }
__device__ __forceinline__ bf16  f2b(float x) { return __float2bfloat16(x); }
__device__ __forceinline__ float u2f(unsigned x) { return __uint_as_float(x); }
// dual-dtype raw-input load: fp32 or bf16 depending on runtime flag
__device__ __forceinline__ float ld(const void* p, size_t i, int f32) {
  return f32 ? ((const float*)p)[i] : b2f(((const bf16*)p)[i]);
}

// ---------------- dtype detector ----------------
__global__ void detect_kernel(const void* q, int* flag) {
  if (threadIdx.x == 0) {
    const unsigned short* u = (const unsigned short*)q;
    int f = 0;
    for (int i = 0; i < 128; i++) {
      unsigned e = (u[i] >> 7) & 0xFF;
      if (e >= 141) f = 1;
    }
    *flag = f;
  }
}

// ---------------- feat transpose: (6,128,h,w) -> (6,h,w,128) ----------------
__global__ __launch_bounds__(256) void tfeat_kernel(const void* __restrict__ in,
                                                    bf16* __restrict__ out, int h, int w,
                                                    const int* flag) {
  int f = *flag;
  int idx = blockIdx.x * 256 + threadIdx.x;
  int c = idx & 127;
  int rest = idx >> 7;
  int x = rest % w;
  int rest2 = rest / w;
  int y = rest2 % h;
  int n = rest2 / h;
  out[idx] = f2b(ld(in, (size_t)((n * 128 + c) * h + y) * w + x, f));
}

// ---------------- weight transpose: [K,N] -> [N,K] ----------------
__global__ __launch_bounds__(256) void tw_kernel(const void* __restrict__ in,
                                                 bf16* __restrict__ out, int K, int N,
                                                 const int* flag) {
  int f = *flag;
  int idx = blockIdx.x * 256 + threadIdx.x;
  if (idx >= K * N) return;
  int n = idx % N, k = idx / N;
  out[n * K + k] = f2b(ld(in, idx, f));
}

// ---------------- S1: logits+softmax+projection, one thread per (q,p) row ----------------
__global__ __launch_bounds__(256) void logit_proj_kernel(
    const void* __restrict__ query,      // [320000,128] raw
    const void* __restrict__ query_pos,  // [8,40000,3] raw
    const void* __restrict__ l2i,        // [6,4,4] raw
    const void* __restrict__ W_sw,       // [128,16] raw
    const void* __restrict__ b_sw,       // [16] raw
    float* __restrict__ swG,             // [320000,16]
    float* __restrict__ uG, float* __restrict__ vG, int* __restrict__ cvG,
    const int* flag) {
  const int f32 = *flag;
  const int t = threadIdx.x;
  const int row0 = blockIdx.x * 256;
  __shared__ float As[256][33];
  __shared__ float wswS[2048];
  __shared__ float bswS[16];
  for (int i = t; i < 2048; i += 256) wswS[i] = ld(W_sw, i, f32);
  if (t < 16) bswS[t] = ld(b_sw, t, f32);
  float acc[16];
  #pragma unroll
  for (int c = 0; c < 16; c++) acc[c] = 0.f;
  for (int k0 = 0; k0 < 128; k0 += 32) {
    __syncthreads();
    for (int i = t; i < 8192; i += 256) {
      int r = i >> 5, kk = i & 31;
      As[r][kk] = ld(query, (size_t)(row0 + r) * 128 + k0 + kk, f32);
    }
    __syncthreads();
    for (int kk = 0; kk < 32; kk++) {
      float a = As[t][kk];
      #pragma unroll
      for (int c = 0; c < 16; c++) acc[c] += a * wswS[(k0 + kk) * 16 + c];
    }
  }
  const int row = row0 + t;
  #pragma unroll
  for (int c = 0; c < 16; c++) acc[c] += bswS[c];
  #pragma unroll
  for (int g = 0; g < 4; g++) {
    float a0 = acc[4 * g], a1 = acc[4 * g + 1], a2 = acc[4 * g + 2], a3 = acc[4 * g + 3];
    float mx = fmaxf(fmaxf(a0, a1), fmaxf(a2, a3));
    float e0 = expf(a0 - mx), e1 = expf(a1 - mx), e2 = expf(a2 - mx), e3 = expf(a3 - mx);
    float inv = 1.f / (e0 + e1 + e2 + e3);
    swG[(size_t)row * 16 + 4 * g]     = e0 * inv;
    swG[(size_t)row * 16 + 4 * g + 1] = e1 * inv;
    swG[(size_t)row * 16 + 4 * g + 2] = e2 * inv;
    swG[(size_t)row * 16 + 4 * g + 3] = e3 * inv;
  }
  // projection
  int q = row >> 3, p = row & 7;
  float q0 = ld(query_pos, ((size_t)p * 40000 + q) * 3 + 0, f32);
  float q1 = ld(query_pos, ((size_t)p * 40000 + q) * 3 + 1, f32);
  float q2 = ld(query_pos, ((size_t)p * 40000 + q) * 3 + 2, f32);
  float px = q0 * 100.f - 50.f;
  float py = q1 * 100.f - 50.f;
  float pz = q2 * 8.f - 4.f;
  int cam = 0, found = 0;
  float usel = 0.f, vsel = 0.f;
  for (int n = 0; n < 6; n++) {
    float m[12];
    #pragma unroll
    for (int i = 0; i < 12; i++) m[i] = ld(l2i, n * 16 + i, f32);
    float c0 = m[0] * px + m[1] * py + m[2] * pz + m[3];
    float c1 = m[4] * px + m[5] * py + m[6] * pz + m[7];
    float c2 = m[8] * px + m[9] * py + m[10] * pz + m[11];
    float d = fmaxf(c2, 1e-6f);
    float u = (c0 / d) / 480.f;
    float v = (c1 / d) / 224.f;
    int valid = (c2 > 1e-6f) && (u > 0.f) && (u < 1.f) && (v > 0.f) && (v < 1.f);
    if (valid && !found) { found = 1; cam = n; usel = u; vsel = v; }
  }
  uG[row] = usel; vG[row] = vsel; cvG[row] = cam | (found << 3);
}

// ---------------- S2: gather, one wave per (q,p) row; lane owns 2 channels ----------------
// Row scalars forced to SGPR via readfirstlane (address math -> SALU);
// corner loads unconditional with OOB mask folded into the bilinear weight.
__global__ __launch_bounds__(256) void gather_kernel(
    const float* __restrict__ swG, const float* __restrict__ uG,
    const float* __restrict__ vG, const int* __restrict__ cvG,
    const bf16* __restrict__ ft, bf16* __restrict__ X) {
  const int t = threadIdx.x;
  const int lane = t & 63;
  const int row = blockIdx.x * 4 + (t >> 6);
  const unsigned* ftU = (const unsigned*)ft;
  unsigned* XU = (unsigned*)X;
  float acc0 = 0.f, acc1 = 0.f;
  const int cv = __builtin_amdgcn_readfirstlane(cvG[row]);
  if (cv & 8) {
    const float u = u2f(__builtin_amdgcn_readfirstlane(__float_as_uint(uG[row])));
    const float v = u2f(__builtin_amdgcn_readfirstlane(__float_as_uint(vG[row])));
    const int cam = cv & 7;
    // per-lane level weights: one dwordx4
    const float4 wl = *(const float4*)(&swG[(size_t)row * 16 + (lane >> 4) * 4]);
    const int LH[4] = {56, 28, 14, 7}, LW[4] = {120, 60, 30, 15};
    const int FOFFU[4] = {0, 2580480, 3225600, 3386880};  // uint-elem offsets
    #pragma unroll
    for (int l = 0; l < 4; l++) {
      const int h = LH[l], w = LW[l];
      const unsigned* fbase = ftU + FOFFU[l] + cam * h * w * 64;
      float x = u * w - 0.5f, y = v * h - 0.5f;
      float x0f = floorf(x), y0f = floorf(y);
      float wx = x - x0f, wy = y - y0f;
      int x0 = (int)x0f, y0 = (int)y0f;
      int x0c = min(max(x0, 0), w - 1), x1c = min(max(x0 + 1, 0), w - 1);
      int y0c = min(max(y0, 0), h - 1), y1c = min(max(y0 + 1, 0), h - 1);
      float mx0 = (x0 >= 0 && x0 < w) ? 1.f : 0.f;
      float mx1 = (x0 + 1 < w) ? 1.f : 0.f;   // x0+1 >= 0 always when mask matters
      float my0 = (y0 >= 0 && y0 < h) ? 1.f : 0.f;
      float my1 = (y0 + 1 < h) ? 1.f : 0.f;
      float c00 = (1.f - wx) * (1.f - wy) * mx0 * my0;
      float c10 = wx * (1.f - wy) * mx1 * my0;
      float c01 = (1.f - wx) * wy * mx0 * my1;
      float c11 = wx * wy * mx1 * my1;
      // scalar corner offsets -> SALU address math, scalar-base loads
      const int o00 = __builtin_amdgcn_readfirstlane((y0c * w + x0c) * 64);
      const int o10 = __builtin_amdgcn_readfirstlane((y0c * w + x1c) * 64);
      const int o01 = __builtin_amdgcn_readfirstlane((y1c * w + x0c) * 64);
      const int o11 = __builtin_amdgcn_readfirstlane((y1c * w + x1c) * 64);
      const unsigned v00 = fbase[o00 + lane];
      const unsigned v10 = fbase[o10 + lane];
      const unsigned v01 = fbase[o01 + lane];
      const unsigned v11 = fbase[o11 + lane];
      float b0 = u2f(v00 << 16) * c00 + u2f(v10 << 16) * c10
               + u2f(v01 << 16) * c01 + u2f(v11 << 16) * c11;
      float b1 = u2f(v00 & 0xFFFF0000u) * c00 + u2f(v10 & 0xFFFF0000u) * c10
               + u2f(v01 & 0xFFFF0000u) * c01 + u2f(v11 & 0xFFFF0000u) * c11;
      const float wlv = (l == 0) ? wl.x : (l == 1) ? wl.y : (l == 2) ? wl.z : wl.w;
      acc0 += wlv * b0;
      acc1 += wlv * b1;
    }
  }
  unsigned lo = (unsigned)(unsigned short)__bfloat16_as_ushort(f2b(acc0));
  unsigned hi = (unsigned)(unsigned short)__bfloat16_as_ushort(f2b(acc1));
  XU[(size_t)row * 64 + lane] = lo | (hi << 16);
}

// ---------------- bf16 MFMA GEMM: C = relu?(A[M,K] @ Bt[N,K]^T + bias) ----------------
__global__ __launch_bounds__(256) void gemm_bt(
    const bf16* __restrict__ A, const bf16* __restrict__ Bt, const void* __restrict__ bias,
    bf16* __restrict__ Cd, float* __restrict__ Cf,
    int M, int N, int K, int relu, int trans_out, const int* flag) {
  __shared__ bf16 As[64 * 40];
  __shared__ bf16 Bs[64 * 40];
  const int f32 = *flag;
  const int t = threadIdx.x;
  const int bm = blockIdx.x * 64;
  const int bn = blockIdx.y * 64;
  const int wv = t >> 6, lane = t & 63;
  const int wm = (wv >> 1) * 32, wn = (wv & 1) * 32;
  const int quad = lane >> 4, l15 = lane & 15;
  const int srow = t >> 2, scol = (t & 3) * 8;
  floatx4 acc[2][2] = {};
  for (int k0 = 0; k0 < K; k0 += 32) {
    *(uint4*)(&As[srow * 40 + scol]) = *(const uint4*)(&A[(size_t)(bm + srow) * K + k0 + scol]);
    *(uint4*)(&Bs[srow * 40 + scol]) = *(const uint4*)(&Bt[(size_t)(bn + srow) * K + k0 + scol]);
    __syncthreads();
    short8 af[2], bfr[2];
    af[0]  = *(const short8*)(&As[(wm + l15) * 40 + quad * 8]);
    af[1]  = *(const short8*)(&As[(wm + 16 + l15) * 40 + quad * 8]);
    bfr[0] = *(const short8*)(&Bs[(wn + l15) * 40 + quad * 8]);
    bfr[1] = *(const short8*)(&Bs[(wn + 16 + l15) * 40 + quad * 8]);
    #pragma unroll
    for (int mi = 0; mi < 2; mi++)
      #pragma unroll
      for (int ni = 0; ni < 2; ni++)
        acc[mi][ni] = __builtin_amdgcn_mfma_f32_16x16x32_bf16(af[mi], bfr[ni], acc[mi][ni], 0, 0, 0);
    __syncthreads();
  }
  #pragma unroll
  for (int mi = 0; mi < 2; mi++)
    #pragma unroll
    for (int ni = 0; ni < 2; ni++) {
      int gn = bn + wn + ni * 16 + l15;
      float bv = ld(bias, gn, f32);
      #pragma unroll
      for (int r = 0; r < 4; r++) {
        int gm = bm + wm + mi * 16 + quad * 4 + r;
        float v = acc[mi][ni][r] + bv;
        if (relu) v = fmaxf(v, 0.f);
        if (trans_out) Cf[(size_t)gn * M + gm] = v;
        else           Cd[(size_t)gm * N + gn] = f2b(v);
      }
    }
}

// ---------------- pos_emb GEMM: X[q*8+z][e] += MLP(query_pos)[e] ----------------
// One block = 64 rows x full N=128. First-layer weights cached in LDS
// (XOR-swizzled 16B units so the 4 scol-groups hit distinct banks); hidden
// activations built in registers and written with a single ds_write_b128.
__global__ __launch_bounds__(256) void gemm_pe(
    const void* __restrict__ query_pos, const void* __restrict__ pe_w1,
    const void* __restrict__ pe_b1, const void* __restrict__ pe_b2,
    const bf16* __restrict__ pw2t, bf16* __restrict__ X, const int* flag) {
  __shared__ bf16 As[64 * 40];    // hidden tile, 64 rows x 32 k
  __shared__ bf16 Bs[128 * 40];   // pw2t tile, 128 n-rows x 32 k
  __shared__ float w1S[256 * 4];  // [k]{w1_0,w1_1,w1_2,b1}, unit-swizzled
  __shared__ float qpS[64 * 3];
  const int f32 = *flag;
  const int t = threadIdx.x;
  const int bm = blockIdx.x * 64;
  const int wv = t >> 6, lane = t & 63;
  const int wm = (wv & 1) * 32, wn = (wv >> 1) * 64;
  const int quad = lane >> 4, l15 = lane & 15;
  const int srow = t >> 2, scol = (t & 3) * 8;
  // stage w1/b1 once: unit k lives at swizzled unit (k ^ ((k>>3)&7))
  for (int i = t; i < 1024; i += 256) {
    int k = i >> 2, c = i & 3;
    int ku = k ^ ((k >> 3) & 7);
    w1S[ku * 4 + c] = (c < 3) ? ld(pe_w1, c * 256 + k, f32) : ld(pe_b1, k, f32);
  }
  if (t < 64) {
    int r = bm + t, qq = r >> 3, zz = r & 7;
    #pragma unroll
    for (int i = 0; i < 3; i++)
      qpS[t * 3 + i] = ld(query_pos, ((size_t)zz * 40000 + qq) * 3 + i, f32);
  }
  __syncthreads();
  const float a0 = qpS[srow * 3], a1 = qpS[srow * 3 + 1], a2 = qpS[srow * 3 + 2];
  floatx4 acc[2][4] = {};
  for (int k0 = 0; k0 < 256; k0 += 32) {
    // A-tile: 8 hidden activations per thread, one b128 LDS write
    short8 hv;
    #pragma unroll
    for (int j = 0; j < 8; j++) {
      int k = k0 + scol + j;
      int ku = k ^ ((k >> 3) & 7);
      const float* wr = &w1S[ku * 4];
      float h = fmaf(a0, wr[0], fmaf(a1, wr[1], fmaf(a2, wr[2], wr[3])));
      hv[j] = (short)__bfloat16_as_ushort(f2b(fmaxf(h, 0.f)));
    }
    *(short8*)(&As[srow * 40 + scol]) = hv;
    // B-tile: 128 rows x 32 k, two uint4 per thread (each element once/block)
    #pragma unroll
    for (int rep = 0; rep < 2; rep++) {
      int linear = rep * 256 + t;
      int brow = linear >> 2, bcol = (linear & 3) * 8;
      *(uint4*)(&Bs[brow * 40 + bcol]) =
          *(const uint4*)(&pw2t[(size_t)brow * 256 + k0 + bcol]);
    }
    __syncthreads();
    short8 af[2], bfr[4];
    #pragma unroll
    for (int mi = 0; mi < 2; mi++)
      af[mi] = *(const short8*)(&As[(wm + mi * 16 + l15) * 40 + quad * 8]);
    #pragma unroll
    for (int ni = 0; ni < 4; ni++)
      bfr[ni] = *(const short8*)(&Bs[(wn + ni * 16 + l15) * 40 + quad * 8]);
    #pragma unroll
    for (int mi = 0; mi < 2; mi++)
      #pragma unroll
      for (int ni = 0; ni < 4; ni++)
        acc[mi][ni] = __builtin_amdgcn_mfma_f32_16x16x32_bf16(af[mi], bfr[ni], acc[mi][ni], 0, 0, 0);
    __syncthreads();
  }
  #pragma unroll
  for (int mi = 0; mi < 2; mi++)
    #pragma unroll
    for (int ni = 0; ni < 4; ni++) {
      int gn = wn + ni * 16 + l15;
      float bv = ld(pe_b2, gn, f32);
      #pragma unroll
      for (int r = 0; r < 4; r++) {
        int gm = bm + wm + mi * 16 + quad * 4 + r;
        size_t off = (size_t)gm * 128 + gn;
        X[off] = f2b(acc[mi][ni][r] + bv + b2f(X[off]));
      }
    }
}

extern "C" void kernel_launch(void* const* d_in, const int* in_sizes, int n_in,
                              void* d_out, int out_size, void* d_ws, size_t ws_size,
                              hipStream_t stream) {
  int* flag = (int*)d_ws;
  bf16* ws = (bf16*)d_ws;
  bf16* ft   = ws + 5760;                // 6,854,400
  bf16* wt1  = ws + 6860160;             // 512x1024
  bf16* wt2  = ws + 7384448;             // 512x512
  bf16* wt3  = ws + 7646592;             // 512x512
  bf16* wt4  = ws + 7908736;             // 128x512
  bf16* pw2t = ws + 7974272;             // 128x256
  bf16* X    = ws + 8007040;             // 40000x1024
  bf16* Ha   = ws + 48967040;            // 40000x512   (ws total ~139 MB)
  bf16* Hb   = X;                        // alias: X dead after layer-1 GEMM
  // sampling scratch aliased onto Ha (dead until layer-1 GEMM writes it)
  float* swG = (float*)Ha;               // 320000x16 fp32 (10.24M be)
  float* uG  = (float*)(ws + 59207040);  // 320000 fp32
  float* vG  = (float*)(ws + 59847040);  // 320000 fp32
  int*   cvG = (int*)(ws + 60487040);    // 320000 int (ends 61127040 < Ha end)

  detect_kernel<<<1, 64, 0, stream>>>(d_in[4], flag);

  tfeat_kernel<<<20160, 256, 0, stream>>>(d_in[0], ft, 56, 120, flag);
  tfeat_kernel<<<5040, 256, 0, stream>>>(d_in[1], ft + 5160960, 28, 60, flag);
  tfeat_kernel<<<1260, 256, 0, stream>>>(d_in[2], ft + 6451200, 14, 30, flag);
  tfeat_kernel<<<315, 256, 0, stream>>>(d_in[3], ft + 6773760, 7, 15, flag);
  tw_kernel<<<2048, 256, 0, stream>>>(d_in[13], wt1, 1024, 512, flag);
  tw_kernel<<<1024, 256, 0, stream>>>(d_in[15], wt2, 512, 512, flag);
  tw_kernel<<<1024, 256, 0, stream>>>(d_in[17], wt3, 512, 512, flag);
  tw_kernel<<<256, 256, 0, stream>>>(d_in[19], wt4, 512, 128, flag);
  tw_kernel<<<128, 256, 0, stream>>>(d_in[11], pw2t, 256, 128, flag);

  logit_proj_kernel<<<1250, 256, 0, stream>>>(d_in[4], d_in[5], d_in[6], d_in[7], d_in[8],
                                              swG, uG, vG, cvG, flag);
  gather_kernel<<<80000, 256, 0, stream>>>(swG, uG, vG, cvG, ft, X);
  gemm_pe<<<5000, 256, 0, stream>>>(d_in[5], d_in[9], d_in[10], d_in[12],
                                    pw2t, X, flag);

  gemm_bt<<<dim3(625, 8), 256, 0, stream>>>(X,  wt1, d_in[14], Ha, nullptr, 40000, 512, 1024, 1, 0, flag);
  gemm_bt<<<dim3(625, 8), 256, 0, stream>>>(Ha, wt2, d_in[16], Hb, nullptr, 40000, 512, 512, 1, 0, flag);
  gemm_bt<<<dim3(625, 8), 256, 0, stream>>>(Hb, wt3, d_in[18], Ha, nullptr, 40000, 512, 512, 1, 0, flag);
  gemm_bt<<<dim3(625, 2), 256, 0, stream>>>(Ha, wt4, d_in[20], nullptr, (float*)d_out, 40000, 128, 512, 0, 1, flag);
}

// Round 4
// 843.007 us; speedup vs baseline: 1.5052x; 1.1336x over previous
//
#include <hip/hip_runtime.h>
#include <hip/hip_bf16.h>

using bf16 = __hip_bfloat16;
typedef __attribute__((ext_vector_type(8))) short short8;
typedef __attribute__((ext_vector_type(4))) float floatx4;

__device__ __forceinline__ float b2f(bf16 x) { return __bfloat162float(x); }
__device__ __forceinline__ bf16  f2b(float x) { return __float2bfloat16(x); }
__device__ __forceinline__ float u2f(unsigned x) { return __uint_as_float(x); }
// dual-dtype raw-input load: fp32 or bf16 depending on runtime flag
__device__ __forceinline__ float ld(const void* p, size_t i, int f32) {
  return f32 ? ((const float*)p)[i] : b2f(((const bf16*)p)[i]);
}

// ---------------- dtype detector ----------------
__global__ void detect_kernel(const void* q, int* flag) {
  if (threadIdx.x == 0) {
    const unsigned short* u = (const unsigned short*)q;
    int f = 0;
    for (int i = 0; i < 128; i++) {
      unsigned e = (u[i] >> 7) & 0xFF;
      if (e >= 141) f = 1;
    }
    *flag = f;
  }
}

// ---------------- feat transpose: (6,128,h,w) -> (6,h,w,128) ----------------
__global__ __launch_bounds__(256) void tfeat_kernel(const void* __restrict__ in,
                                                    bf16* __restrict__ out, int h, int w,
                                                    const int* flag) {
  int f = *flag;
  int idx = blockIdx.x * 256 + threadIdx.x;
  int c = idx & 127;
  int rest = idx >> 7;
  int x = rest % w;
  int rest2 = rest / w;
  int y = rest2 % h;
  int n = rest2 / h;
  out[idx] = f2b(ld(in, (size_t)((n * 128 + c) * h + y) * w + x, f));
}

// ---------------- weight transpose: [K,N] -> [N,K] ----------------
__global__ __launch_bounds__(256) void tw_kernel(const void* __restrict__ in,
                                                 bf16* __restrict__ out, int K, int N,
                                                 const int* flag) {
  int f = *flag;
  int idx = blockIdx.x * 256 + threadIdx.x;
  if (idx >= K * N) return;
  int n = idx % N, k = idx / N;
  out[n * K + k] = f2b(ld(in, idx, f));
}

// ---------------- S1: logits (MFMA) + softmax (shuffle) + projection ----------------
// Block = 256 threads = 4 waves; wave owns 64 rows x 16 logit channels.
// W^T fragments live in registers (loaded once); A fragments loaded directly
// from global (lane l: row=l&15, 16B contiguous) -- no LDS staging at all.
__global__ __launch_bounds__(256) void logit_proj_kernel(
    const void* __restrict__ query,      // [320000,128] raw
    const void* __restrict__ query_pos,  // [8,40000,3] raw
    const void* __restrict__ l2i,        // [6,4,4] raw (96 elems total!)
    const bf16* __restrict__ wswT,       // [16,128] bf16 (pre-transposed)
    const void* __restrict__ b_sw,       // [16] raw
    float* __restrict__ swG,             // [320000,16]
    float* __restrict__ uG, float* __restrict__ vG, int* __restrict__ cvG,
    const int* flag) {
  const int f32 = *flag;
  const int t = threadIdx.x;
  const int lane = t & 63;
  const int wv = t >> 6;
  const int row0b = blockIdx.x * 256;
  const int row0w = row0b + wv * 64;
  const int quad = lane >> 4, l15 = lane & 15;
  __shared__ float l2iS[96];
  __shared__ float bswS[16];
  if (t < 72) l2iS[t] = ld(l2i, (t / 12) * 16 + (t % 12), f32);  // 6 cams x 12 entries
  if (t >= 96 && t < 112) bswS[t - 96] = ld(b_sw, t - 96, f32);
  // B fragments: one short8 per 32-k step, resident for the whole kernel
  short8 bfr[4];
  #pragma unroll
  for (int ks = 0; ks < 4; ks++)
    bfr[ks] = *(const short8*)(&wswT[l15 * 128 + ks * 32 + quad * 8]);
  __syncthreads();
  floatx4 acc[4] = {};
  #pragma unroll
  for (int ks = 0; ks < 4; ks++) {
    #pragma unroll
    for (int mt = 0; mt < 4; mt++) {
      const size_t off = (size_t)(row0w + mt * 16 + l15) * 128 + ks * 32 + quad * 8;
      short8 af;
      if (f32) {
        const float* qf = (const float*)query + off;
        #pragma unroll
        for (int j = 0; j < 8; j++) af[j] = (short)__bfloat16_as_ushort(f2b(qf[j]));
      } else {
        af = *(const short8*)((const bf16*)query + off);
      }
      acc[mt] = __builtin_amdgcn_mfma_f32_16x16x32_bf16(af, bfr[ks], acc[mt], 0, 0, 0);
    }
  }
  // bias + softmax over 4-channel groups (4 adjacent lanes) + store
  const float bias = bswS[l15];
  #pragma unroll
  for (int mt = 0; mt < 4; mt++) {
    #pragma unroll
    for (int r = 0; r < 4; r++) {
      float x = acc[mt][r] + bias;
      float m = fmaxf(x, __shfl_xor(x, 1));
      m = fmaxf(m, __shfl_xor(m, 2));
      float e = expf(x - m);
      float s = e + __shfl_xor(e, 1);
      s += __shfl_xor(s, 2);
      const int rowG = row0w + mt * 16 + quad * 4 + r;
      swG[(size_t)rowG * 16 + l15] = e / s;
    }
  }
  // projection: thread t handles row row0b + t
  const int row = row0b + t;
  int q = row >> 3, p = row & 7;
  float q0 = ld(query_pos, ((size_t)p * 40000 + q) * 3 + 0, f32);
  float q1 = ld(query_pos, ((size_t)p * 40000 + q) * 3 + 1, f32);
  float q2 = ld(query_pos, ((size_t)p * 40000 + q) * 3 + 2, f32);
  float px = q0 * 100.f - 50.f;
  float py = q1 * 100.f - 50.f;
  float pz = q2 * 8.f - 4.f;
  int cam = 0, found = 0;
  float usel = 0.f, vsel = 0.f;
  for (int n = 0; n < 6; n++) {
    const float* m = &l2iS[n * 12];
    float c0 = m[0] * px + m[1] * py + m[2] * pz + m[3];
    float c1 = m[4] * px + m[5] * py + m[6] * pz + m[7];
    float c2 = m[8] * px + m[9] * py + m[10] * pz + m[11];
    float d = fmaxf(c2, 1e-6f);
    float u = (c0 / d) / 480.f;
    float v = (c1 / d) / 224.f;
    int valid = (c2 > 1e-6f) && (u > 0.f) && (u < 1.f) && (v > 0.f) && (v < 1.f);
    if (valid && !found) { found = 1; cam = n; usel = u; vsel = v; }
  }
  uG[row] = usel; vG[row] = vsel; cvG[row] = cam | (found << 3);
}

// ---------------- S2: gather, one wave per (q,p) row; lane owns 2 channels ----------------
// Row scalars forced to SGPR via readfirstlane (address math -> SALU);
// corner loads unconditional with OOB mask folded into the bilinear weight.
__global__ __launch_bounds__(256) void gather_kernel(
    const float* __restrict__ swG, const float* __restrict__ uG,
    const float* __restrict__ vG, const int* __restrict__ cvG,
    const bf16* __restrict__ ft, bf16* __restrict__ X) {
  const int t = threadIdx.x;
  const int lane = t & 63;
  const int row = blockIdx.x * 4 + (t >> 6);
  const unsigned* ftU = (const unsigned*)ft;
  unsigned* XU = (unsigned*)X;
  float acc0 = 0.f, acc1 = 0.f;
  const int cv = __builtin_amdgcn_readfirstlane(cvG[row]);
  if (cv & 8) {
    const float u = u2f(__builtin_amdgcn_readfirstlane(__float_as_uint(uG[row])));
    const float v = u2f(__builtin_amdgcn_readfirstlane(__float_as_uint(vG[row])));
    const int cam = cv & 7;
    // per-lane level weights: one dwordx4
    const float4 wl = *(const float4*)(&swG[(size_t)row * 16 + (lane >> 4) * 4]);
    const int LH[4] = {56, 28, 14, 7}, LW[4] = {120, 60, 30, 15};
    const int FOFFU[4] = {0, 2580480, 3225600, 3386880};  // uint-elem offsets
    #pragma unroll
    for (int l = 0; l < 4; l++) {
      const int h = LH[l], w = LW[l];
      const unsigned* fbase = ftU + FOFFU[l] + cam * h * w * 64;
      float x = u * w - 0.5f, y = v * h - 0.5f;
      float x0f = floorf(x), y0f = floorf(y);
      float wx = x - x0f, wy = y - y0f;
      int x0 = (int)x0f, y0 = (int)y0f;
      int x0c = min(max(x0, 0), w - 1), x1c = min(max(x0 + 1, 0), w - 1);
      int y0c = min(max(y0, 0), h - 1), y1c = min(max(y0 + 1, 0), h - 1);
      float mx0 = (x0 >= 0 && x0 < w) ? 1.f : 0.f;
      float mx1 = (x0 + 1 < w) ? 1.f : 0.f;   // x0+1 >= 0 always when mask matters
      float my0 = (y0 >= 0 && y0 < h) ? 1.f : 0.f;
      float my1 = (y0 + 1 < h) ? 1.f : 0.f;
      float c00 = (1.f - wx) * (1.f - wy) * mx0 * my0;
      float c10 = wx * (1.f - wy) * mx1 * my0;
      float c01 = (1.f - wx) * wy * mx0 * my1;
      float c11 = wx * wy * mx1 * my1;
      // scalar corner offsets -> SALU address math, scalar-base loads
      const int o00 = __builtin_amdgcn_readfirstlane((y0c * w + x0c) * 64);
      const int o10 = __builtin_amdgcn_readfirstlane((y0c * w + x1c) * 64);
      const int o01 = __builtin_amdgcn_readfirstlane((y1c * w + x0c) * 64);
      const int o11 = __builtin_amdgcn_readfirstlane((y1c * w + x1c) * 64);
      const unsigned v00 = fbase[o00 + lane];
      const unsigned v10 = fbase[o10 + lane];
      const unsigned v01 = fbase[o01 + lane];
      const unsigned v11 = fbase[o11 + lane];
      float b0 = u2f(v00 << 16) * c00 + u2f(v10 << 16) * c10
               + u2f(v01 << 16) * c01 + u2f(v11 << 16) * c11;
      float b1 = u2f(v00 & 0xFFFF0000u) * c00 + u2f(v10 & 0xFFFF0000u) * c10
               + u2f(v01 & 0xFFFF0000u) * c01 + u2f(v11 & 0xFFFF0000u) * c11;
      const float wlv = (l == 0) ? wl.x : (l == 1) ? wl.y : (l == 2) ? wl.z : wl.w;
      acc0 += wlv * b0;
      acc1 += wlv * b1;
    }
  }
  unsigned lo = (unsigned)(unsigned short)__bfloat16_as_ushort(f2b(acc0));
  unsigned hi = (unsigned)(unsigned short)__bfloat16_as_ushort(f2b(acc1));
  XU[(size_t)row * 64 + lane] = lo | (hi << 16);
}

// ---------------- bf16 MFMA GEMM: C = relu?(A[M,K] @ Bt[N,K]^T + bias) ----------------
__global__ __launch_bounds__(256) void gemm_bt(
    const bf16* __restrict__ A, const bf16* __restrict__ Bt, const void* __restrict__ bias,
    bf16* __restrict__ Cd, float* __restrict__ Cf,
    int M, int N, int K, int relu, int trans_out, const int* flag) {
  __shared__ bf16 As[64 * 40];
  __shared__ bf16 Bs[64 * 40];
  const int f32 = *flag;
  const int t = threadIdx.x;
  const int bm = blockIdx.x * 64;
  const int bn = blockIdx.y * 64;
  const int wv = t >> 6, lane = t & 63;
  const int wm = (wv >> 1) * 32, wn = (wv & 1) * 32;
  const int quad = lane >> 4, l15 = lane & 15;
  const int srow = t >> 2, scol = (t & 3) * 8;
  floatx4 acc[2][2] = {};
  for (int k0 = 0; k0 < K; k0 += 32) {
    *(uint4*)(&As[srow * 40 + scol]) = *(const uint4*)(&A[(size_t)(bm + srow) * K + k0 + scol]);
    *(uint4*)(&Bs[srow * 40 + scol]) = *(const uint4*)(&Bt[(size_t)(bn + srow) * K + k0 + scol]);
    __syncthreads();
    short8 af[2], bfr[2];
    af[0]  = *(const short8*)(&As[(wm + l15) * 40 + quad * 8]);
    af[1]  = *(const short8*)(&As[(wm + 16 + l15) * 40 + quad * 8]);
    bfr[0] = *(const short8*)(&Bs[(wn + l15) * 40 + quad * 8]);
    bfr[1] = *(const short8*)(&Bs[(wn + 16 + l15) * 40 + quad * 8]);
    #pragma unroll
    for (int mi = 0; mi < 2; mi++)
      #pragma unroll
      for (int ni = 0; ni < 2; ni++)
        acc[mi][ni] = __builtin_amdgcn_mfma_f32_16x16x32_bf16(af[mi], bfr[ni], acc[mi][ni], 0, 0, 0);
    __syncthreads();
  }
  #pragma unroll
  for (int mi = 0; mi < 2; mi++)
    #pragma unroll
    for (int ni = 0; ni < 2; ni++) {
      int gn = bn + wn + ni * 16 + l15;
      float bv = ld(bias, gn, f32);
      #pragma unroll
      for (int r = 0; r < 4; r++) {
        int gm = bm + wm + mi * 16 + quad * 4 + r;
        float v = acc[mi][ni][r] + bv;
        if (relu) v = fmaxf(v, 0.f);
        if (trans_out) Cf[(size_t)gn * M + gm] = v;
        else           Cd[(size_t)gm * N + gn] = f2b(v);
      }
    }
}

// ---------------- pos_emb GEMM: X[q*8+z][e] += MLP(query_pos)[e] ----------------
// One block = 64 rows x full N=128. First-layer weights cached in LDS
// (XOR-swizzled 16B units so the 4 scol-groups hit distinct banks); hidden
// activations built in registers and written with a single ds_write_b128.
__global__ __launch_bounds__(256) void gemm_pe(
    const void* __restrict__ query_pos, const void* __restrict__ pe_w1,
    const void* __restrict__ pe_b1, const void* __restrict__ pe_b2,
    const bf16* __restrict__ pw2t, bf16* __restrict__ X, const int* flag) {
  __shared__ bf16 As[64 * 40];    // hidden tile, 64 rows x 32 k
  __shared__ bf16 Bs[128 * 40];   // pw2t tile, 128 n-rows x 32 k
  __shared__ float w1S[256 * 4];  // [k]{w1_0,w1_1,w1_2,b1}, unit-swizzled
  __shared__ float qpS[64 * 3];
  const int f32 = *flag;
  const int t = threadIdx.x;
  const int bm = blockIdx.x * 64;
  const int wv = t >> 6, lane = t & 63;
  const int wm = (wv & 1) * 32, wn = (wv >> 1) * 64;
  const int quad = lane >> 4, l15 = lane & 15;
  const int srow = t >> 2, scol = (t & 3) * 8;
  // stage w1/b1 once: unit k lives at swizzled unit (k ^ ((k>>3)&7))
  for (int i = t; i < 1024; i += 256) {
    int k = i >> 2, c = i & 3;
    int ku = k ^ ((k >> 3) & 7);
    w1S[ku * 4 + c] = (c < 3) ? ld(pe_w1, c * 256 + k, f32) : ld(pe_b1, k, f32);
  }
  if (t < 64) {
    int r = bm + t, qq = r >> 3, zz = r & 7;
    #pragma unroll
    for (int i = 0; i < 3; i++)
      qpS[t * 3 + i] = ld(query_pos, ((size_t)zz * 40000 + qq) * 3 + i, f32);
  }
  __syncthreads();
  const float a0 = qpS[srow * 3], a1 = qpS[srow * 3 + 1], a2 = qpS[srow * 3 + 2];
  floatx4 acc[2][4] = {};
  for (int k0 = 0; k0 < 256; k0 += 32) {
    // A-tile: 8 hidden activations per thread, one b128 LDS write
    short8 hv;
    #pragma unroll
    for (int j = 0; j < 8; j++) {
      int k = k0 + scol + j;
      int ku = k ^ ((k >> 3) & 7);
      const float* wr = &w1S[ku * 4];
      float h = fmaf(a0, wr[0], fmaf(a1, wr[1], fmaf(a2, wr[2], wr[3])));
      hv[j] = (short)__bfloat16_as_ushort(f2b(fmaxf(h, 0.f)));
    }
    *(short8*)(&As[srow * 40 + scol]) = hv;
    // B-tile: 128 rows x 32 k, two uint4 per thread (each element once/block)
    #pragma unroll
    for (int rep = 0; rep < 2; rep++) {
      int linear = rep * 256 + t;
      int brow = linear >> 2, bcol = (linear & 3) * 8;
      *(uint4*)(&Bs[brow * 40 + bcol]) =
          *(const uint4*)(&pw2t[(size_t)brow * 256 + k0 + bcol]);
    }
    __syncthreads();
    short8 af[2], bfr[4];
    #pragma unroll
    for (int mi = 0; mi < 2; mi++)
      af[mi] = *(const short8*)(&As[(wm + mi * 16 + l15) * 40 + quad * 8]);
    #pragma unroll
    for (int ni = 0; ni < 4; ni++)
      bfr[ni] = *(const short8*)(&Bs[(wn + ni * 16 + l15) * 40 + quad * 8]);
    #pragma unroll
    for (int mi = 0; mi < 2; mi++)
      #pragma unroll
      for (int ni = 0; ni < 4; ni++)
        acc[mi][ni] = __builtin_amdgcn_mfma_f32_16x16x32_bf16(af[mi], bfr[ni], acc[mi][ni], 0, 0, 0);
    __syncthreads();
  }
  #pragma unroll
  for (int mi = 0; mi < 2; mi++)
    #pragma unroll
    for (int ni = 0; ni < 4; ni++) {
      int gn = wn + ni * 16 + l15;
      float bv = ld(pe_b2, gn, f32);
      #pragma unroll
      for (int r = 0; r < 4; r++) {
        int gm = bm + wm + mi * 16 + quad * 4 + r;
        size_t off = (size_t)gm * 128 + gn;
        X[off] = f2b(acc[mi][ni][r] + bv + b2f(X[off]));
      }
    }
}

extern "C" void kernel_launch(void* const* d_in, const int* in_sizes, int n_in,
                              void* d_out, int out_size, void* d_ws, size_t ws_size,
                              hipStream_t stream) {
  int* flag = (int*)d_ws;
  bf16* ws = (bf16*)d_ws;
  bf16* wswT = ws + 1024;                // 16x128 bf16 (logit W^T), fits in gap < 5760
  bf16* ft   = ws + 5760;                // 6,854,400
  bf16* wt1  = ws + 6860160;             // 512x1024
  bf16* wt2  = ws + 7384448;             // 512x512
  bf16* wt3  = ws + 7646592;             // 512x512
  bf16* wt4  = ws + 7908736;             // 128x512
  bf16* pw2t = ws + 7974272;             // 128x256
  bf16* X    = ws + 8007040;             // 40000x1024
  bf16* Ha   = ws + 48967040;            // 40000x512   (ws total ~139 MB)
  bf16* Hb   = X;                        // alias: X dead after layer-1 GEMM
  // sampling scratch aliased onto Ha (dead until layer-1 GEMM writes it)
  float* swG = (float*)Ha;               // 320000x16 fp32 (10.24M be)
  float* uG  = (float*)(ws + 59207040);  // 320000 fp32
  float* vG  = (float*)(ws + 59847040);  // 320000 fp32
  int*   cvG = (int*)(ws + 60487040);    // 320000 int (ends 61127040 < Ha end)

  detect_kernel<<<1, 64, 0, stream>>>(d_in[4], flag);

  tfeat_kernel<<<20160, 256, 0, stream>>>(d_in[0], ft, 56, 120, flag);
  tfeat_kernel<<<5040, 256, 0, stream>>>(d_in[1], ft + 5160960, 28, 60, flag);
  tfeat_kernel<<<1260, 256, 0, stream>>>(d_in[2], ft + 6451200, 14, 30, flag);
  tfeat_kernel<<<315, 256, 0, stream>>>(d_in[3], ft + 6773760, 7, 15, flag);
  tw_kernel<<<2048, 256, 0, stream>>>(d_in[13], wt1, 1024, 512, flag);
  tw_kernel<<<1024, 256, 0, stream>>>(d_in[15], wt2, 512, 512, flag);
  tw_kernel<<<1024, 256, 0, stream>>>(d_in[17], wt3, 512, 512, flag);
  tw_kernel<<<256, 256, 0, stream>>>(d_in[19], wt4, 512, 128, flag);
  tw_kernel<<<128, 256, 0, stream>>>(d_in[11], pw2t, 256, 128, flag);
  tw_kernel<<<8, 256, 0, stream>>>(d_in[7], wswT, 128, 16, flag);

  logit_proj_kernel<<<1250, 256, 0, stream>>>(d_in[4], d_in[5], d_in[6], wswT, d_in[8],
                                              swG, uG, vG, cvG, flag);
  gather_kernel<<<80000, 256, 0, stream>>>(swG, uG, vG, cvG, ft, X);
  gemm_pe<<<5000, 256, 0, stream>>>(d_in[5], d_in[9], d_in[10], d_in[12],
                                    pw2t, X, flag);

  gemm_bt<<<dim3(625, 8), 256, 0, stream>>>(X,  wt1, d_in[14], Ha, nullptr, 40000, 512, 1024, 1, 0, flag);
  gemm_bt<<<dim3(625, 8), 256, 0, stream>>>(Ha, wt2, d_in[16], Hb, nullptr, 40000, 512, 512, 1, 0, flag);
  gemm_bt<<<dim3(625, 8), 256, 0, stream>>>(Hb, wt3, d_in[18], Ha, nullptr, 40000, 512, 512, 1, 0, flag);
  gemm_bt<<<dim3(625, 2), 256, 0, stream>>>(Ha, wt4, d_in[20], nullptr, (float*)d_out, 40000, 128, 512, 0, 1, flag);
}

// Round 5
// 798.761 us; speedup vs baseline: 1.5886x; 1.0554x over previous
//
#include <hip/hip_runtime.h>
#include <hip/hip_bf16.h>
#include <hip/hip_fp16.h>

using bf16 = __hip_bfloat16;
typedef __attribute__((ext_vector_type(8))) short short8;
typedef __attribute__((ext_vector_type(4))) float floatx4;

__device__ __forceinline__ float b2f(bf16 x) { return __bfloat162float(x); }
__device__ __forceinline__ bf16  f2b(float x) { return __float2bfloat16(x); }
__device__ __forceinline__ float u2f(unsigned x) { return __uint_as_float(x); }
// dual-dtype raw-input load: fp32 or bf16 depending on runtime flag
__device__ __forceinline__ float ld(const void* p, size_t i, int f32) {
  return f32 ? ((const float*)p)[i] : b2f(((const bf16*)p)[i]);
}

// ---------------- dtype detector ----------------
__global__ void detect_kernel(const void* q, int* flag) {
  if (threadIdx.x == 0) {
    const unsigned short* u = (const unsigned short*)q;
    int f = 0;
    for (int i = 0; i < 128; i++) {
      unsigned e = (u[i] >> 7) & 0xFF;
      if (e >= 141) f = 1;
    }
    *flag = f;
  }
}

// ---------------- feat transpose: (6,128,h,w) -> (6,h,w,128), output f16 ----------------
__global__ __launch_bounds__(256) void tfeat_kernel(const void* __restrict__ in,
                                                    __half* __restrict__ out, int h, int w,
                                                    const int* flag) {
  int f = *flag;
  int idx = blockIdx.x * 256 + threadIdx.x;
  int c = idx & 127;
  int rest = idx >> 7;
  int x = rest % w;
  int rest2 = rest / w;
  int y = rest2 % h;
  int n = rest2 / h;
  out[idx] = __float2half(ld(in, (size_t)((n * 128 + c) * h + y) * w + x, f));
}

// ---------------- weight transpose: [K,N] -> [N,K] ----------------
__global__ __launch_bounds__(256) void tw_kernel(const void* __restrict__ in,
                                                 bf16* __restrict__ out, int K, int N,
                                                 const int* flag) {
  int f = *flag;
  int idx = blockIdx.x * 256 + threadIdx.x;
  if (idx >= K * N) return;
  int n = idx % N, k = idx / N;
  out[n * K + k] = f2b(ld(in, idx, f));
}

// ---------------- S1: logits (MFMA) + softmax (shuffle) + projection ----------------
// Block = 256 threads = 4 waves; wave owns 64 rows x 16 logit channels.
// W^T fragments live in registers (loaded once); A fragments loaded directly
// from global (lane l: row=l&15, 16B contiguous) -- no LDS staging at all.
__global__ __launch_bounds__(256) void logit_proj_kernel(
    const void* __restrict__ query,      // [320000,128] raw
    const void* __restrict__ query_pos,  // [8,40000,3] raw
    const void* __restrict__ l2i,        // [6,4,4] raw (96 elems total!)
    const bf16* __restrict__ wswT,       // [16,128] bf16 (pre-transposed)
    const void* __restrict__ b_sw,       // [16] raw
    float* __restrict__ swG,             // [320000,16]
    float* __restrict__ uG, float* __restrict__ vG, int* __restrict__ cvG,
    const int* flag) {
  const int f32 = *flag;
  const int t = threadIdx.x;
  const int lane = t & 63;
  const int wv = t >> 6;
  const int row0b = blockIdx.x * 256;
  const int row0w = row0b + wv * 64;
  const int quad = lane >> 4, l15 = lane & 15;
  __shared__ float l2iS[96];
  __shared__ float bswS[16];
  if (t < 72) l2iS[t] = ld(l2i, (t / 12) * 16 + (t % 12), f32);  // 6 cams x 12 entries
  if (t >= 96 && t < 112) bswS[t - 96] = ld(b_sw, t - 96, f32);
  // B fragments: one short8 per 32-k step, resident for the whole kernel
  short8 bfr[4];
  #pragma unroll
  for (int ks = 0; ks < 4; ks++)
    bfr[ks] = *(const short8*)(&wswT[l15 * 128 + ks * 32 + quad * 8]);
  __syncthreads();
  floatx4 acc[4] = {};
  #pragma unroll
  for (int ks = 0; ks < 4; ks++) {
    #pragma unroll
    for (int mt = 0; mt < 4; mt++) {
      const size_t off = (size_t)(row0w + mt * 16 + l15) * 128 + ks * 32 + quad * 8;
      short8 af;
      if (f32) {
        const float* qf = (const float*)query + off;
        #pragma unroll
        for (int j = 0; j < 8; j++) af[j] = (short)__bfloat16_as_ushort(f2b(qf[j]));
      } else {
        af = *(const short8*)((const bf16*)query + off);
      }
      acc[mt] = __builtin_amdgcn_mfma_f32_16x16x32_bf16(af, bfr[ks], acc[mt], 0, 0, 0);
    }
  }
  // bias + softmax over 4-channel groups (4 adjacent lanes) + store
  const float bias = bswS[l15];
  #pragma unroll
  for (int mt = 0; mt < 4; mt++) {
    #pragma unroll
    for (int r = 0; r < 4; r++) {
      float x = acc[mt][r] + bias;
      float m = fmaxf(x, __shfl_xor(x, 1));
      m = fmaxf(m, __shfl_xor(m, 2));
      float e = expf(x - m);
      float s = e + __shfl_xor(e, 1);
      s += __shfl_xor(s, 2);
      const int rowG = row0w + mt * 16 + quad * 4 + r;
      swG[(size_t)rowG * 16 + l15] = e / s;
    }
  }
  // projection: thread t handles row row0b + t
  const int row = row0b + t;
  int q = row >> 3, p = row & 7;
  float q0 = ld(query_pos, ((size_t)p * 40000 + q) * 3 + 0, f32);
  float q1 = ld(query_pos, ((size_t)p * 40000 + q) * 3 + 1, f32);
  float q2 = ld(query_pos, ((size_t)p * 40000 + q) * 3 + 2, f32);
  float px = q0 * 100.f - 50.f;
  float py = q1 * 100.f - 50.f;
  float pz = q2 * 8.f - 4.f;
  int cam = 0, found = 0;
  float usel = 0.f, vsel = 0.f;
  for (int n = 0; n < 6; n++) {
    const float* m = &l2iS[n * 12];
    float c0 = m[0] * px + m[1] * py + m[2] * pz + m[3];
    float c1 = m[4] * px + m[5] * py + m[6] * pz + m[7];
    float c2 = m[8] * px + m[9] * py + m[10] * pz + m[11];
    float d = fmaxf(c2, 1e-6f);
    float u = (c0 / d) / 480.f;
    float v = (c1 / d) / 224.f;
    int valid = (c2 > 1e-6f) && (u > 0.f) && (u < 1.f) && (v > 0.f) && (v < 1.f);
    if (valid && !found) { found = 1; cam = n; usel = u; vsel = v; }
  }
  uG[row] = usel; vG[row] = vsel; cvG[row] = cam | (found << 3);
}

// ---------------- S2: gather, one wave per (q,p) row ----------------
// Level-parallel lanes: level = lane>>4; 16 lanes per level, each lane owns
// 8 channels (one dwordx4 of f16 per corner). Per-level setup computed once
// per lane-group (not 4x per lane); f16 features consumed via fma_mix
// (__low2float/__high2float, no unpack); cross-level reduce = 2-step
// shfl_xor butterfly; lanes 0-15 store one dwordx4 of packed bf16.
__global__ __launch_bounds__(256) void gather_kernel(
    const float* __restrict__ swG, const float* __restrict__ uG,
    const float* __restrict__ vG, const int* __restrict__ cvG,
    const __half* __restrict__ ft, bf16* __restrict__ X) {
  const int t = threadIdx.x;
  const int lane = t & 63;
  const int row = blockIdx.x * 4 + (t >> 6);
  const int lvl = lane >> 4;
  const int l15 = lane & 15;
  float acc[8];
  #pragma unroll
  for (int k = 0; k < 8; k++) acc[k] = 0.f;
  const int cv = __builtin_amdgcn_readfirstlane(cvG[row]);
  if (cv & 8) {
    const float u = u2f(__builtin_amdgcn_readfirstlane(__float_as_uint(uG[row])));
    const float v = u2f(__builtin_amdgcn_readfirstlane(__float_as_uint(vG[row])));
    const int cam = cv & 7;
    // this lane's level geometry
    const int h = 56 >> lvl;            // 56,28,14,7
    const int w = 120 >> lvl;           // 120,60,30,15
    // level base in uint4 units: cumulative {0,645120,806400,846720}
    const int fo4 = (lvl == 0) ? 0 : (lvl == 1) ? 645120 : (lvl == 2) ? 806400 : 846720;
    const int hw16 = h * w * 16;        // uint4 per camera at this level
    // softmax weight for (group g = l15>>2, level lvl)
    const float wl = swG[(size_t)row * 16 + (l15 >> 2) * 4 + lvl];
    // bilinear setup (this level only)
    float x = u * w - 0.5f, y = v * h - 0.5f;
    float x0f = floorf(x), y0f = floorf(y);
    float wx = x - x0f, wy = y - y0f;
    int x0 = (int)x0f, y0 = (int)y0f;
    int x0c = min(max(x0, 0), w - 1), x1c = min(max(x0 + 1, 0), w - 1);
    int y0c = min(max(y0, 0), h - 1), y1c = min(max(y0 + 1, 0), h - 1);
    float mx0 = (x0 >= 0 && x0 < w) ? wl : 0.f;
    float mx1 = (x0 + 1 < w) ? wl : 0.f;
    float my0 = (y0 >= 0 && y0 < h) ? 1.f : 0.f;
    float my1 = (y0 + 1 < h) ? 1.f : 0.f;
    const float c00 = (1.f - wx) * (1.f - wy) * mx0 * my0;
    const float c10 = wx * (1.f - wy) * mx1 * my0;
    const float c01 = (1.f - wx) * wy * mx0 * my1;
    const float c11 = wx * wy * mx1 * my1;
    const uint4* fb = (const uint4*)ft + fo4 + cam * hw16 + l15;
    const int o00 = (y0c * w + x0c) * 16;
    const int o10 = (y0c * w + x1c) * 16;
    const int o01 = (y1c * w + x0c) * 16;
    const int o11 = (y1c * w + x1c) * 16;
    const uint4 d00 = fb[o00];
    const uint4 d10 = fb[o10];
    const uint4 d01 = fb[o01];
    const uint4 d11 = fb[o11];
    #pragma unroll
    for (int c = 0; c < 4; c++) {
      const uint4& d = (c == 0) ? d00 : (c == 1) ? d10 : (c == 2) ? d01 : d11;
      const float cw = (c == 0) ? c00 : (c == 1) ? c10 : (c == 2) ? c01 : c11;
      const __half2* hp = reinterpret_cast<const __half2*>(&d);
      #pragma unroll
      for (int j = 0; j < 4; j++) {
        acc[2 * j]     += __low2float(hp[j]) * cw;
        acc[2 * j + 1] += __high2float(hp[j]) * cw;
      }
    }
    // cross-level reduce: partners are lane, lane^16, lane^32 (+48)
    #pragma unroll
    for (int k = 0; k < 8; k++) {
      acc[k] += __shfl_xor(acc[k], 16);
      acc[k] += __shfl_xor(acc[k], 32);
    }
  }
  if (lane < 16) {
    uint4 o;
    unsigned p0 = (unsigned)(unsigned short)__bfloat16_as_ushort(f2b(acc[0]))
                | ((unsigned)(unsigned short)__bfloat16_as_ushort(f2b(acc[1])) << 16);
    unsigned p1 = (unsigned)(unsigned short)__bfloat16_as_ushort(f2b(acc[2]))
                | ((unsigned)(unsigned short)__bfloat16_as_ushort(f2b(acc[3])) << 16);
    unsigned p2 = (unsigned)(unsigned short)__bfloat16_as_ushort(f2b(acc[4]))
                | ((unsigned)(unsigned short)__bfloat16_as_ushort(f2b(acc[5])) << 16);
    unsigned p3 = (unsigned)(unsigned short)__bfloat16_as_ushort(f2b(acc[6]))
                | ((unsigned)(unsigned short)__bfloat16_as_ushort(f2b(acc[7])) << 16);
    o.x = p0; o.y = p1; o.z = p2; o.w = p3;
    ((uint4*)X)[(size_t)row * 16 + l15] = o;
  }
}

// ---------------- bf16 MFMA GEMM: C = relu?(A[M,K] @ Bt[N,K]^T + bias) ----------------
__global__ __launch_bounds__(256) void gemm_bt(
    const bf16* __restrict__ A, const bf16* __restrict__ Bt, const void* __restrict__ bias,
    bf16* __restrict__ Cd, float* __restrict__ Cf,
    int M, int N, int K, int relu, int trans_out, const int* flag) {
  __shared__ bf16 As[64 * 40];
  __shared__ bf16 Bs[64 * 40];
  const int f32 = *flag;
  const int t = threadIdx.x;
  const int bm = blockIdx.x * 64;
  const int bn = blockIdx.y * 64;
  const int wv = t >> 6, lane = t & 63;
  const int wm = (wv >> 1) * 32, wn = (wv & 1) * 32;
  const int quad = lane >> 4, l15 = lane & 15;
  const int srow = t >> 2, scol = (t & 3) * 8;
  floatx4 acc[2][2] = {};
  for (int k0 = 0; k0 < K; k0 += 32) {
    *(uint4*)(&As[srow * 40 + scol]) = *(const uint4*)(&A[(size_t)(bm + srow) * K + k0 + scol]);
    *(uint4*)(&Bs[srow * 40 + scol]) = *(const uint4*)(&Bt[(size_t)(bn + srow) * K + k0 + scol]);
    __syncthreads();
    short8 af[2], bfr[2];
    af[0]  = *(const short8*)(&As[(wm + l15) * 40 + quad * 8]);
    af[1]  = *(const short8*)(&As[(wm + 16 + l15) * 40 + quad * 8]);
    bfr[0] = *(const short8*)(&Bs[(wn + l15) * 40 + quad * 8]);
    bfr[1] = *(const short8*)(&Bs[(wn + 16 + l15) * 40 + quad * 8]);
    #pragma unroll
    for (int mi = 0; mi < 2; mi++)
      #pragma unroll
      for (int ni = 0; ni < 2; ni++)
        acc[mi][ni] = __builtin_amdgcn_mfma_f32_16x16x32_bf16(af[mi], bfr[ni], acc[mi][ni], 0, 0, 0);
    __syncthreads();
  }
  #pragma unroll
  for (int mi = 0; mi < 2; mi++)
    #pragma unroll
    for (int ni = 0; ni < 2; ni++) {
      int gn = bn + wn + ni * 16 + l15;
      float bv = ld(bias, gn, f32);
      #pragma unroll
      for (int r = 0; r < 4; r++) {
        int gm = bm + wm + mi * 16 + quad * 4 + r;
        float v = acc[mi][ni][r] + bv;
        if (relu) v = fmaxf(v, 0.f);
        if (trans_out) Cf[(size_t)gn * M + gm] = v;
        else           Cd[(size_t)gm * N + gn] = f2b(v);
      }
    }
}

// ---------------- pos_emb GEMM: X[q*8+z][e] += MLP(query_pos)[e] ----------------
// One block = 64 rows x full N=128. First-layer weights cached in LDS
// (XOR-swizzled 16B units so the 4 scol-groups hit distinct banks); hidden
// activations built in registers and written with a single ds_write_b128.
__global__ __launch_bounds__(256) void gemm_pe(
    const void* __restrict__ query_pos, const void* __restrict__ pe_w1,
    const void* __restrict__ pe_b1, const void* __restrict__ pe_b2,
    const bf16* __restrict__ pw2t, bf16* __restrict__ X, const int* flag) {
  __shared__ bf16 As[64 * 40];    // hidden tile, 64 rows x 32 k
  __shared__ bf16 Bs[128 * 40];   // pw2t tile, 128 n-rows x 32 k
  __shared__ float w1S[256 * 4];  // [k]{w1_0,w1_1,w1_2,b1}, unit-swizzled
  __shared__ float qpS[64 * 3];
  const int f32 = *flag;
  const int t = threadIdx.x;
  const int bm = blockIdx.x * 64;
  const int wv = t >> 6, lane = t & 63;
  const int wm = (wv & 1) * 32, wn = (wv >> 1) * 64;
  const int quad = lane >> 4, l15 = lane & 15;
  const int srow = t >> 2, scol = (t & 3) * 8;
  // stage w1/b1 once: unit k lives at swizzled unit (k ^ ((k>>3)&7))
  for (int i = t; i < 1024; i += 256) {
    int k = i >> 2, c = i & 3;
    int ku = k ^ ((k >> 3) & 7);
    w1S[ku * 4 + c] = (c < 3) ? ld(pe_w1, c * 256 + k, f32) : ld(pe_b1, k, f32);
  }
  if (t < 64) {
    int r = bm + t, qq = r >> 3, zz = r & 7;
    #pragma unroll
    for (int i = 0; i < 3; i++)
      qpS[t * 3 + i] = ld(query_pos, ((size_t)zz * 40000 + qq) * 3 + i, f32);
  }
  __syncthreads();
  const float a0 = qpS[srow * 3], a1 = qpS[srow * 3 + 1], a2 = qpS[srow * 3 + 2];
  floatx4 acc[2][4] = {};
  for (int k0 = 0; k0 < 256; k0 += 32) {
    // A-tile: 8 hidden activations per thread, one b128 LDS write
    short8 hv;
    #pragma unroll
    for (int j = 0; j < 8; j++) {
      int k = k0 + scol + j;
      int ku = k ^ ((k >> 3) & 7);
      const float* wr = &w1S[ku * 4];
      float h = fmaf(a0, wr[0], fmaf(a1, wr[1], fmaf(a2, wr[2], wr[3])));
      hv[j] = (short)__bfloat16_as_ushort(f2b(fmaxf(h, 0.f)));
    }
    *(short8*)(&As[srow * 40 + scol]) = hv;
    // B-tile: 128 rows x 32 k, two uint4 per thread (each element once/block)
    #pragma unroll
    for (int rep = 0; rep < 2; rep++) {
      int linear = rep * 256 + t;
      int brow = linear >> 2, bcol = (linear & 3) * 8;
      *(uint4*)(&Bs[brow * 40 + bcol]) =
          *(const uint4*)(&pw2t[(size_t)brow * 256 + k0 + bcol]);
    }
    __syncthreads();
    short8 af[2], bfr[4];
    #pragma unroll
    for (int mi = 0; mi < 2; mi++)
      af[mi] = *(const short8*)(&As[(wm + mi * 16 + l15) * 40 + quad * 8]);
    #pragma unroll
    for (int ni = 0; ni < 4; ni++)
      bfr[ni] = *(const short8*)(&Bs[(wn + ni * 16 + l15) * 40 + quad * 8]);
    #pragma unroll
    for (int mi = 0; mi < 2; mi++)
      #pragma unroll
      for (int ni = 0; ni < 4; ni++)
        acc[mi][ni] = __builtin_amdgcn_mfma_f32_16x16x32_bf16(af[mi], bfr[ni], acc[mi][ni], 0, 0, 0);
    __syncthreads();
  }
  #pragma unroll
  for (int mi = 0; mi < 2; mi++)
    #pragma unroll
    for (int ni = 0; ni < 4; ni++) {
      int gn = wn + ni * 16 + l15;
      float bv = ld(pe_b2, gn, f32);
      #pragma unroll
      for (int r = 0; r < 4; r++) {
        int gm = bm + wm + mi * 16 + quad * 4 + r;
        size_t off = (size_t)gm * 128 + gn;
        X[off] = f2b(acc[mi][ni][r] + bv + b2f(X[off]));
      }
    }
}

extern "C" void kernel_launch(void* const* d_in, const int* in_sizes, int n_in,
                              void* d_out, int out_size, void* d_ws, size_t ws_size,
                              hipStream_t stream) {
  int* flag = (int*)d_ws;
  bf16* ws = (bf16*)d_ws;
  bf16* wswT = ws + 1024;                // 16x128 bf16 (logit W^T), fits in gap < 5760
  bf16* ft   = ws + 5760;                // 6,854,400 (stored as f16)
  bf16* wt1  = ws + 6860160;             // 512x1024
  bf16* wt2  = ws + 7384448;             // 512x512
  bf16* wt3  = ws + 7646592;             // 512x512
  bf16* wt4  = ws + 7908736;             // 128x512
  bf16* pw2t = ws + 7974272;             // 128x256
  bf16* X    = ws + 8007040;             // 40000x1024
  bf16* Ha   = ws + 48967040;            // 40000x512   (ws total ~139 MB)
  bf16* Hb   = X;                        // alias: X dead after layer-1 GEMM
  // sampling scratch aliased onto Ha (dead until layer-1 GEMM writes it)
  float* swG = (float*)Ha;               // 320000x16 fp32 (10.24M be)
  float* uG  = (float*)(ws + 59207040);  // 320000 fp32
  float* vG  = (float*)(ws + 59847040);  // 320000 fp32
  int*   cvG = (int*)(ws + 60487040);    // 320000 int (ends 61127040 < Ha end)

  detect_kernel<<<1, 64, 0, stream>>>(d_in[4], flag);

  tfeat_kernel<<<20160, 256, 0, stream>>>(d_in[0], (__half*)ft, 56, 120, flag);
  tfeat_kernel<<<5040, 256, 0, stream>>>(d_in[1], (__half*)(ft + 5160960), 28, 60, flag);
  tfeat_kernel<<<1260, 256, 0, stream>>>(d_in[2], (__half*)(ft + 6451200), 14, 30, flag);
  tfeat_kernel<<<315, 256, 0, stream>>>(d_in[3], (__half*)(ft + 6773760), 7, 15, flag);
  tw_kernel<<<2048, 256, 0, stream>>>(d_in[13], wt1, 1024, 512, flag);
  tw_kernel<<<1024, 256, 0, stream>>>(d_in[15], wt2, 512, 512, flag);
  tw_kernel<<<1024, 256, 0, stream>>>(d_in[17], wt3, 512, 512, flag);
  tw_kernel<<<256, 256, 0, stream>>>(d_in[19], wt4, 512, 128, flag);
  tw_kernel<<<128, 256, 0, stream>>>(d_in[11], pw2t, 256, 128, flag);
  tw_kernel<<<8, 256, 0, stream>>>(d_in[7], wswT, 128, 16, flag);

  logit_proj_kernel<<<1250, 256, 0, stream>>>(d_in[4], d_in[5], d_in[6], wswT, d_in[8],
                                              swG, uG, vG, cvG, flag);
  gather_kernel<<<80000, 256, 0, stream>>>(swG, uG, vG, cvG, (const __half*)ft, X);
  gemm_pe<<<5000, 256, 0, stream>>>(d_in[5], d_in[9], d_in[10], d_in[12],
                                    pw2t, X, flag);

  gemm_bt<<<dim3(625, 8), 256, 0, stream>>>(X,  wt1, d_in[14], Ha, nullptr, 40000, 512, 1024, 1, 0, flag);
  gemm_bt<<<dim3(625, 8), 256, 0, stream>>>(Ha, wt2, d_in[16], Hb, nullptr, 40000, 512, 512, 1, 0, flag);
  gemm_bt<<<dim3(625, 8), 256, 0, stream>>>(Hb, wt3, d_in[18], Ha, nullptr, 40000, 512, 512, 1, 0, flag);
  gemm_bt<<<dim3(625, 2), 256, 0, stream>>>(Ha, wt4, d_in[20], nullptr, (float*)d_out, 40000, 128, 512, 0, 1, flag);
}

// Round 6
// 739.013 us; speedup vs baseline: 1.7170x; 1.0808x over previous
//
#include <hip/hip_runtime.h>
#include <hip/hip_bf16.h>
#include <hip/hip_fp16.h>

using bf16 = __hip_bfloat16;
typedef __attribute__((ext_vector_type(8))) short short8;
typedef __attribute__((ext_vector_type(4))) float floatx4;

__device__ __forceinline__ float b2f(bf16 x) { return __bfloat162float(x); }
__device__ __forceinline__ bf16  f2b(float x) { return __float2bfloat16(x); }
__device__ __forceinline__ float u2f(unsigned x) { return __uint_as_float(x); }
// dual-dtype raw-input load: fp32 or bf16 depending on runtime flag
__device__ __forceinline__ float ld(const void* p, size_t i, int f32) {
  return f32 ? ((const float*)p)[i] : b2f(((const bf16*)p)[i]);
}
// async global->LDS, 16B per lane; lds dest must be wave-uniform base
__device__ __forceinline__ void gload16(const bf16* g, bf16* l) {
  __builtin_amdgcn_global_load_lds(
      (const __attribute__((address_space(1))) unsigned int*)(g),
      (__attribute__((address_space(3))) unsigned int*)(l), 16, 0, 0);
}

// ---------------- dtype detector ----------------
__global__ void detect_kernel(const void* q, int* flag) {
  if (threadIdx.x == 0) {
    const unsigned short* u = (const unsigned short*)q;
    int f = 0;
    for (int i = 0; i < 128; i++) {
      unsigned e = (u[i] >> 7) & 0xFF;
      if (e >= 141) f = 1;
    }
    *flag = f;
  }
}

// ---------------- feat transpose: (6,128,h,w) -> (6,h,w,128), output f16 ----------------
__global__ __launch_bounds__(256) void tfeat_kernel(const void* __restrict__ in,
                                                    __half* __restrict__ out, int h, int w,
                                                    const int* flag) {
  int f = *flag;
  int idx = blockIdx.x * 256 + threadIdx.x;
  int c = idx & 127;
  int rest = idx >> 7;
  int x = rest % w;
  int rest2 = rest / w;
  int y = rest2 % h;
  int n = rest2 / h;
  out[idx] = __float2half(ld(in, (size_t)((n * 128 + c) * h + y) * w + x, f));
}

// ---------------- weight transpose: [K,N] -> [N,K] ----------------
__global__ __launch_bounds__(256) void tw_kernel(const void* __restrict__ in,
                                                 bf16* __restrict__ out, int K, int N,
                                                 const int* flag) {
  int f = *flag;
  int idx = blockIdx.x * 256 + threadIdx.x;
  if (idx >= K * N) return;
  int n = idx % N, k = idx / N;
  out[n * K + k] = f2b(ld(in, idx, f));
}

// ---------------- S1: logits (MFMA) + softmax (shuffle) + projection ----------------
__global__ __launch_bounds__(256) void logit_proj_kernel(
    const void* __restrict__ query,      // [320000,128] raw
    const void* __restrict__ query_pos,  // [8,40000,3] raw
    const void* __restrict__ l2i,        // [6,4,4] raw (96 elems total!)
    const bf16* __restrict__ wswT,       // [16,128] bf16 (pre-transposed)
    const void* __restrict__ b_sw,       // [16] raw
    float* __restrict__ swG,             // [320000,16]
    float* __restrict__ uG, float* __restrict__ vG, int* __restrict__ cvG,
    const int* flag) {
  const int f32 = *flag;
  const int t = threadIdx.x;
  const int lane = t & 63;
  const int wv = t >> 6;
  const int row0b = blockIdx.x * 256;
  const int row0w = row0b + wv * 64;
  const int quad = lane >> 4, l15 = lane & 15;
  __shared__ float l2iS[96];
  __shared__ float bswS[16];
  if (t < 72) l2iS[t] = ld(l2i, (t / 12) * 16 + (t % 12), f32);  // 6 cams x 12 entries
  if (t >= 96 && t < 112) bswS[t - 96] = ld(b_sw, t - 96, f32);
  short8 bfr[4];
  #pragma unroll
  for (int ks = 0; ks < 4; ks++)
    bfr[ks] = *(const short8*)(&wswT[l15 * 128 + ks * 32 + quad * 8]);
  __syncthreads();
  floatx4 acc[4] = {};
  #pragma unroll
  for (int ks = 0; ks < 4; ks++) {
    #pragma unroll
    for (int mt = 0; mt < 4; mt++) {
      const size_t off = (size_t)(row0w + mt * 16 + l15) * 128 + ks * 32 + quad * 8;
      short8 af;
      if (f32) {
        const float* qf = (const float*)query + off;
        #pragma unroll
        for (int j = 0; j < 8; j++) af[j] = (short)__bfloat16_as_ushort(f2b(qf[j]));
      } else {
        af = *(const short8*)((const bf16*)query + off);
      }
      acc[mt] = __builtin_amdgcn_mfma_f32_16x16x32_bf16(af, bfr[ks], acc[mt], 0, 0, 0);
    }
  }
  const float bias = bswS[l15];
  #pragma unroll
  for (int mt = 0; mt < 4; mt++) {
    #pragma unroll
    for (int r = 0; r < 4; r++) {
      float x = acc[mt][r] + bias;
      float m = fmaxf(x, __shfl_xor(x, 1));
      m = fmaxf(m, __shfl_xor(m, 2));
      float e = expf(x - m);
      float s = e + __shfl_xor(e, 1);
      s += __shfl_xor(s, 2);
      const int rowG = row0w + mt * 16 + quad * 4 + r;
      swG[(size_t)rowG * 16 + l15] = e / s;
    }
  }
  const int row = row0b + t;
  int q = row >> 3, p = row & 7;
  float q0 = ld(query_pos, ((size_t)p * 40000 + q) * 3 + 0, f32);
  float q1 = ld(query_pos, ((size_t)p * 40000 + q) * 3 + 1, f32);
  float q2 = ld(query_pos, ((size_t)p * 40000 + q) * 3 + 2, f32);
  float px = q0 * 100.f - 50.f;
  float py = q1 * 100.f - 50.f;
  float pz = q2 * 8.f - 4.f;
  int cam = 0, found = 0;
  float usel = 0.f, vsel = 0.f;
  for (int n = 0; n < 6; n++) {
    const float* m = &l2iS[n * 12];
    float c0 = m[0] * px + m[1] * py + m[2] * pz + m[3];
    float c1 = m[4] * px + m[5] * py + m[6] * pz + m[7];
    float c2 = m[8] * px + m[9] * py + m[10] * pz + m[11];
    float d = fmaxf(c2, 1e-6f);
    float u = (c0 / d) / 480.f;
    float v = (c1 / d) / 224.f;
    int valid = (c2 > 1e-6f) && (u > 0.f) && (u < 1.f) && (v > 0.f) && (v < 1.f);
    if (valid && !found) { found = 1; cam = n; usel = u; vsel = v; }
  }
  uG[row] = usel; vG[row] = vsel; cvG[row] = cam | (found << 3);
}

// ---------------- S2: gather, one wave per (q,p) row ----------------
__global__ __launch_bounds__(256) void gather_kernel(
    const float* __restrict__ swG, const float* __restrict__ uG,
    const float* __restrict__ vG, const int* __restrict__ cvG,
    const __half* __restrict__ ft, bf16* __restrict__ X) {
  const int t = threadIdx.x;
  const int lane = t & 63;
  const int row = blockIdx.x * 4 + (t >> 6);
  const int lvl = lane >> 4;
  const int l15 = lane & 15;
  float acc[8];
  #pragma unroll
  for (int k = 0; k < 8; k++) acc[k] = 0.f;
  const int cv = __builtin_amdgcn_readfirstlane(cvG[row]);
  if (cv & 8) {
    const float u = u2f(__builtin_amdgcn_readfirstlane(__float_as_uint(uG[row])));
    const float v = u2f(__builtin_amdgcn_readfirstlane(__float_as_uint(vG[row])));
    const int cam = cv & 7;
    const int h = 56 >> lvl;            // 56,28,14,7
    const int w = 120 >> lvl;           // 120,60,30,15
    const int fo4 = (lvl == 0) ? 0 : (lvl == 1) ? 645120 : (lvl == 2) ? 806400 : 846720;
    const int hw16 = h * w * 16;        // uint4 per camera at this level
    const float wl = swG[(size_t)row * 16 + (l15 >> 2) * 4 + lvl];
    float x = u * w - 0.5f, y = v * h - 0.5f;
    float x0f = floorf(x), y0f = floorf(y);
    float wx = x - x0f, wy = y - y0f;
    int x0 = (int)x0f, y0 = (int)y0f;
    int x0c = min(max(x0, 0), w - 1), x1c = min(max(x0 + 1, 0), w - 1);
    int y0c = min(max(y0, 0), h - 1), y1c = min(max(y0 + 1, 0), h - 1);
    float mx0 = (x0 >= 0 && x0 < w) ? wl : 0.f;
    float mx1 = (x0 + 1 < w) ? wl : 0.f;
    float my0 = (y0 >= 0 && y0 < h) ? 1.f : 0.f;
    float my1 = (y0 + 1 < h) ? 1.f : 0.f;
    const float c00 = (1.f - wx) * (1.f - wy) * mx0 * my0;
    const float c10 = wx * (1.f - wy) * mx1 * my0;
    const float c01 = (1.f - wx) * wy * mx0 * my1;
    const float c11 = wx * wy * mx1 * my1;
    const uint4* fb = (const uint4*)ft + fo4 + cam * hw16 + l15;
    const int o00 = (y0c * w + x0c) * 16;
    const int o10 = (y0c * w + x1c) * 16;
    const int o01 = (y1c * w + x0c) * 16;
    const int o11 = (y1c * w + x1c) * 16;
    const uint4 d00 = fb[o00];
    const uint4 d10 = fb[o10];
    const uint4 d01 = fb[o01];
    const uint4 d11 = fb[o11];
    #pragma unroll
    for (int c = 0; c < 4; c++) {
      const uint4& d = (c == 0) ? d00 : (c == 1) ? d10 : (c == 2) ? d01 : d11;
      const float cw = (c == 0) ? c00 : (c == 1) ? c10 : (c == 2) ? c01 : c11;
      const __half2* hp = reinterpret_cast<const __half2*>(&d);
      #pragma unroll
      for (int j = 0; j < 4; j++) {
        acc[2 * j]     += __low2float(hp[j]) * cw;
        acc[2 * j + 1] += __high2float(hp[j]) * cw;
      }
    }
    #pragma unroll
    for (int k = 0; k < 8; k++) {
      acc[k] += __shfl_xor(acc[k], 16);
      acc[k] += __shfl_xor(acc[k], 32);
    }
  }
  if (lane < 16) {
    uint4 o;
    unsigned p0 = (unsigned)(unsigned short)__bfloat16_as_ushort(f2b(acc[0]))
                | ((unsigned)(unsigned short)__bfloat16_as_ushort(f2b(acc[1])) << 16);
    unsigned p1 = (unsigned)(unsigned short)__bfloat16_as_ushort(f2b(acc[2]))
                | ((unsigned)(unsigned short)__bfloat16_as_ushort(f2b(acc[3])) << 16);
    unsigned p2 = (unsigned)(unsigned short)__bfloat16_as_ushort(f2b(acc[4]))
                | ((unsigned)(unsigned short)__bfloat16_as_ushort(f2b(acc[5])) << 16);
    unsigned p3 = (unsigned)(unsigned short)__bfloat16_as_ushort(f2b(acc[6]))
                | ((unsigned)(unsigned short)__bfloat16_as_ushort(f2b(acc[7])) << 16);
    o.x = p0; o.y = p1; o.z = p2; o.w = p3;
    ((uint4*)X)[(size_t)row * 16 + l15] = o;
  }
}

// ---------------- bf16 MFMA GEMM (m97 structure): 128x128 tile, BK=32 ----------------
// 4 waves, each owns a 64x64 sub-tile (acc[4][4]); LDS filled via
// global_load_lds width-16 (linear dest, pre-swizzled source); one-bit
// st_16x32 XOR swizzle on source+read (involution, rule #21); 2-barrier loop.
// 1D grid with m204 bijective XCD swizzle; consecutive same-XCD blocks share
// the A panel (bm = swz/nbn) for L2 reuse. M-tail: source rows clamped,
// stores guarded.
__global__ __launch_bounds__(256) void gemm_bt(
    const bf16* __restrict__ A, const bf16* __restrict__ Bt, const void* __restrict__ bias,
    bf16* __restrict__ Cd, float* __restrict__ Cf,
    int M, int N, int K, int relu, int trans_out, int nbn, const int* flag) {
  __shared__ bf16 As[128 * 32];
  __shared__ bf16 Bs[128 * 32];
  const int f32 = *flag;
  const int t = threadIdx.x;
  const int lane = t & 63;
  const int wv = t >> 6;
  // XCD-bijective swizzle (m204), then decompose: consecutive swz share bm
  const int nwg = gridDim.x;
  const int lin = blockIdx.x;
  const int q8 = nwg >> 3, r8 = nwg & 7;
  const int xcd = lin & 7, idx8 = lin >> 3;
  const int swz = ((xcd < r8) ? (xcd * (q8 + 1)) : (r8 * (q8 + 1) + (xcd - r8) * q8)) + idx8;
  const int bm = (swz / nbn) * 128;
  const int bn = (swz % nbn) * 128;
  const int wm = (wv >> 1) * 64, wn = (wv & 1) * 64;
  const int quad = lane >> 4, l15 = lane & 15;
  // staging: chunk c = wv*2+r covers LDS bytes [c*1024,(c+1)*1024), lane l -> +l*16
  // source element for lane l (pre-swizzled): row = c*16 + (l>>2),
  // col = (l&3)*8 ^ (l>=32 ? 16 : 0)   [bit9 of dest byte = (l>=32)]
  const int srow = lane >> 2;
  const int scol = ((lane & 3) * 8) ^ ((lane >= 32) ? 16 : 0);
  const int c0 = wv * 2, c1 = wv * 2 + 1;
  int ar0 = min(bm + c0 * 16 + srow, M - 1);
  int ar1 = min(bm + c1 * 16 + srow, M - 1);
  const int br0 = bn + c0 * 16 + srow;
  const int br1 = bn + c1 * 16 + srow;
  const bf16* pa0 = A + (size_t)ar0 * K + scol;
  const bf16* pa1 = A + (size_t)ar1 * K + scol;
  const bf16* pb0 = Bt + (size_t)br0 * K + scol;
  const bf16* pb1 = Bt + (size_t)br1 * K + scol;
  bf16* la0 = &As[c0 * 512];
  bf16* la1 = &As[c1 * 512];
  bf16* lb0 = &Bs[c0 * 512];
  bf16* lb1 = &Bs[c1 * 512];
  // fragment read offsets (swizzled): row ra -> elem ra*32 + (quad*8 ^ ((ra&8)?16:0))
  const int axo = quad * 8 ^ ((l15 & 8) ? 16 : 0);
  floatx4 acc[4][4] = {};
  for (int k0 = 0; k0 < K; k0 += 32) {
    gload16(pa0, la0);
    gload16(pa1, la1);
    gload16(pb0, lb0);
    gload16(pb1, lb1);
    pa0 += 32; pa1 += 32; pb0 += 32; pb1 += 32;
    __syncthreads();
    short8 af[4], bfr[4];
    #pragma unroll
    for (int i = 0; i < 4; i++) {
      af[i]  = *(const short8*)(&As[(wm + i * 16 + l15) * 32 + axo]);
      bfr[i] = *(const short8*)(&Bs[(wn + i * 16 + l15) * 32 + axo]);
    }
    #pragma unroll
    for (int mi = 0; mi < 4; mi++)
      #pragma unroll
      for (int ni = 0; ni < 4; ni++)
        acc[mi][ni] = __builtin_amdgcn_mfma_f32_16x16x32_bf16(af[mi], bfr[ni], acc[mi][ni], 0, 0, 0);
    __syncthreads();
  }
  #pragma unroll
  for (int ni = 0; ni < 4; ni++) {
    const int gn = bn + wn + ni * 16 + l15;
    const float bv = ld(bias, gn, f32);
    #pragma unroll
    for (int mi = 0; mi < 4; mi++) {
      #pragma unroll
      for (int r = 0; r < 4; r++) {
        const int gm = bm + wm + mi * 16 + quad * 4 + r;
        if (gm < M) {
          float v = acc[mi][ni][r] + bv;
          if (relu) v = fmaxf(v, 0.f);
          if (trans_out) Cf[(size_t)gn * M + gm] = v;
          else           Cd[(size_t)gm * N + gn] = f2b(v);
        }
      }
    }
  }
}

// ---------------- pos_emb GEMM: X[q*8+z][e] += MLP(query_pos)[e] ----------------
__global__ __launch_bounds__(256) void gemm_pe(
    const void* __restrict__ query_pos, const void* __restrict__ pe_w1,
    const void* __restrict__ pe_b1, const void* __restrict__ pe_b2,
    const bf16* __restrict__ pw2t, bf16* __restrict__ X, const int* flag) {
  __shared__ bf16 As[64 * 40];    // hidden tile, 64 rows x 32 k
  __shared__ bf16 Bs[128 * 40];   // pw2t tile, 128 n-rows x 32 k
  __shared__ float w1S[256 * 4];  // [k]{w1_0,w1_1,w1_2,b1}, unit-swizzled
  __shared__ float qpS[64 * 3];
  const int f32 = *flag;
  const int t = threadIdx.x;
  const int bm = blockIdx.x * 64;
  const int wv = t >> 6, lane = t & 63;
  const int wm = (wv & 1) * 32, wn = (wv >> 1) * 64;
  const int quad = lane >> 4, l15 = lane & 15;
  const int srow = t >> 2, scol = (t & 3) * 8;
  for (int i = t; i < 1024; i += 256) {
    int k = i >> 2, c = i & 3;
    int ku = k ^ ((k >> 3) & 7);
    w1S[ku * 4 + c] = (c < 3) ? ld(pe_w1, c * 256 + k, f32) : ld(pe_b1, k, f32);
  }
  if (t < 64) {
    int r = bm + t, qq = r >> 3, zz = r & 7;
    #pragma unroll
    for (int i = 0; i < 3; i++)
      qpS[t * 3 + i] = ld(query_pos, ((size_t)zz * 40000 + qq) * 3 + i, f32);
  }
  __syncthreads();
  const float a0 = qpS[srow * 3], a1 = qpS[srow * 3 + 1], a2 = qpS[srow * 3 + 2];
  floatx4 acc[2][4] = {};
  for (int k0 = 0; k0 < 256; k0 += 32) {
    short8 hv;
    #pragma unroll
    for (int j = 0; j < 8; j++) {
      int k = k0 + scol + j;
      int ku = k ^ ((k >> 3) & 7);
      const float* wr = &w1S[ku * 4];
      float h = fmaf(a0, wr[0], fmaf(a1, wr[1], fmaf(a2, wr[2], wr[3])));
      hv[j] = (short)__bfloat16_as_ushort(f2b(fmaxf(h, 0.f)));
    }
    *(short8*)(&As[srow * 40 + scol]) = hv;
    #pragma unroll
    for (int rep = 0; rep < 2; rep++) {
      int linear = rep * 256 + t;
      int brow = linear >> 2, bcol = (linear & 3) * 8;
      *(uint4*)(&Bs[brow * 40 + bcol]) =
          *(const uint4*)(&pw2t[(size_t)brow * 256 + k0 + bcol]);
    }
    __syncthreads();
    short8 af[2], bfr[4];
    #pragma unroll
    for (int mi = 0; mi < 2; mi++)
      af[mi] = *(const short8*)(&As[(wm + mi * 16 + l15) * 40 + quad * 8]);
    #pragma unroll
    for (int ni = 0; ni < 4; ni++)
      bfr[ni] = *(const short8*)(&Bs[(wn + ni * 16 + l15) * 40 + quad * 8]);
    #pragma unroll
    for (int mi = 0; mi < 2; mi++)
      #pragma unroll
      for (int ni = 0; ni < 4; ni++)
        acc[mi][ni] = __builtin_amdgcn_mfma_f32_16x16x32_bf16(af[mi], bfr[ni], acc[mi][ni], 0, 0, 0);
    __syncthreads();
  }
  #pragma unroll
  for (int mi = 0; mi < 2; mi++)
    #pragma unroll
    for (int ni = 0; ni < 4; ni++) {
      int gn = wn + ni * 16 + l15;
      float bv = ld(pe_b2, gn, f32);
      #pragma unroll
      for (int r = 0; r < 4; r++) {
        int gm = bm + wm + mi * 16 + quad * 4 + r;
        size_t off = (size_t)gm * 128 + gn;
        X[off] = f2b(acc[mi][ni][r] + bv + b2f(X[off]));
      }
    }
}

extern "C" void kernel_launch(void* const* d_in, const int* in_sizes, int n_in,
                              void* d_out, int out_size, void* d_ws, size_t ws_size,
                              hipStream_t stream) {
  int* flag = (int*)d_ws;
  bf16* ws = (bf16*)d_ws;
  bf16* wswT = ws + 1024;                // 16x128 bf16 (logit W^T), fits in gap < 5760
  bf16* ft   = ws + 5760;                // 6,854,400 (stored as f16)
  bf16* wt1  = ws + 6860160;             // 512x1024
  bf16* wt2  = ws + 7384448;             // 512x512
  bf16* wt3  = ws + 7646592;             // 512x512
  bf16* wt4  = ws + 7908736;             // 128x512
  bf16* pw2t = ws + 7974272;             // 128x256
  bf16* X    = ws + 8007040;             // 40000x1024
  bf16* Ha   = ws + 48967040;            // 40000x512   (ws total ~139 MB)
  bf16* Hb   = X;                        // alias: X dead after layer-1 GEMM
  // sampling scratch aliased onto Ha (dead until layer-1 GEMM writes it)
  float* swG = (float*)Ha;               // 320000x16 fp32 (10.24M be)
  float* uG  = (float*)(ws + 59207040);  // 320000 fp32
  float* vG  = (float*)(ws + 59847040);  // 320000 fp32
  int*   cvG = (int*)(ws + 60487040);    // 320000 int (ends 61127040 < Ha end)

  detect_kernel<<<1, 64, 0, stream>>>(d_in[4], flag);

  tfeat_kernel<<<20160, 256, 0, stream>>>(d_in[0], (__half*)ft, 56, 120, flag);
  tfeat_kernel<<<5040, 256, 0, stream>>>(d_in[1], (__half*)(ft + 5160960), 28, 60, flag);
  tfeat_kernel<<<1260, 256, 0, stream>>>(d_in[2], (__half*)(ft + 6451200), 14, 30, flag);
  tfeat_kernel<<<315, 256, 0, stream>>>(d_in[3], (__half*)(ft + 6773760), 7, 15, flag);
  tw_kernel<<<2048, 256, 0, stream>>>(d_in[13], wt1, 1024, 512, flag);
  tw_kernel<<<1024, 256, 0, stream>>>(d_in[15], wt2, 512, 512, flag);
  tw_kernel<<<1024, 256, 0, stream>>>(d_in[17], wt3, 512, 512, flag);
  tw_kernel<<<256, 256, 0, stream>>>(d_in[19], wt4, 512, 128, flag);
  tw_kernel<<<128, 256, 0, stream>>>(d_in[11], pw2t, 256, 128, flag);
  tw_kernel<<<8, 256, 0, stream>>>(d_in[7], wswT, 128, 16, flag);

  logit_proj_kernel<<<1250, 256, 0, stream>>>(d_in[4], d_in[5], d_in[6], wswT, d_in[8],
                                              swG, uG, vG, cvG, flag);
  gather_kernel<<<80000, 256, 0, stream>>>(swG, uG, vG, cvG, (const __half*)ft, X);
  gemm_pe<<<5000, 256, 0, stream>>>(d_in[5], d_in[9], d_in[10], d_in[12],
                                    pw2t, X, flag);

  const int nbm = 313;  // ceil(40000/128)
  gemm_bt<<<nbm * 4, 256, 0, stream>>>(X,  wt1, d_in[14], Ha, nullptr, 40000, 512, 1024, 1, 0, 4, flag);
  gemm_bt<<<nbm * 4, 256, 0, stream>>>(Ha, wt2, d_in[16], Hb, nullptr, 40000, 512, 512, 1, 0, 4, flag);
  gemm_bt<<<nbm * 4, 256, 0, stream>>>(Hb, wt3, d_in[18], Ha, nullptr, 40000, 512, 512, 1, 0, 4, flag);
  gemm_bt<<<nbm * 1, 256, 0, stream>>>(Ha, wt4, d_in[20], nullptr, (float*)d_out, 40000, 128, 512, 0, 1, 1, flag);
}

// Round 7
// 714.892 us; speedup vs baseline: 1.7750x; 1.0337x over previous
//
#include <hip/hip_runtime.h>
#include <hip/hip_bf16.h>
#include <hip/hip_fp16.h>

using bf16 = __hip_bfloat16;
typedef __attribute__((ext_vector_type(8))) short short8;
typedef __attribute__((ext_vector_type(4))) float floatx4;

__device__ __forceinline__ float b2f(bf16 x) { return __bfloat162float(x); }
__device__ __forceinline__ bf16  f2b(float x) { return __float2bfloat16(x); }
__device__ __forceinline__ float u2f(unsigned x) { return __uint_as_float(x); }
// dual-dtype raw-input load: fp32 or bf16 depending on runtime flag
__device__ __forceinline__ float ld(const void* p, size_t i, int f32) {
  return f32 ? ((const float*)p)[i] : b2f(((const bf16*)p)[i]);
}
// async global->LDS, 16B per lane; lds dest must be wave-uniform base
__device__ __forceinline__ void gload16(const bf16* g, bf16* l) {
  __builtin_amdgcn_global_load_lds(
      (const __attribute__((address_space(1))) unsigned int*)(g),
      (__attribute__((address_space(3))) unsigned int*)(l), 16, 0, 0);
}

// ---------------- dtype detector ----------------
__global__ void detect_kernel(const void* q, int* flag) {
  if (threadIdx.x == 0) {
    const unsigned short* u = (const unsigned short*)q;
    int f = 0;
    for (int i = 0; i < 128; i++) {
      unsigned e = (u[i] >> 7) & 0xFF;
      if (e >= 141) f = 1;
    }
    *flag = f;
  }
}

// ---------------- feat transpose: (6,128,HW) -> (6,HW,128), f16 out ----------------
// LDS-transpose tile: 32 px x 128 c per block. Read: lane=px (coalesced),
// 16 c per thread packed to f16 pairs, 2x ds_write_b128. Write: 16 c per
// thread via 2x ds_read_b128, 32B contiguous global store (8 thr = 256B).
__global__ __launch_bounds__(256) void tfeat_kernel(const void* __restrict__ in,
                                                    __half* __restrict__ out, int HW,
                                                    const int* flag) {
  __shared__ unsigned short lds[32][136];   // pad 8 ushort: px stride 272B
  const int f = *flag;
  const int n = blockIdx.y;
  const int px0 = blockIdx.x * 32;
  const int t = threadIdx.x;
  const int px = t & 31;
  const int cb = (t >> 5) * 16;
  if (px0 + px < HW) {
    unsigned pk[8];
    #pragma unroll
    for (int i = 0; i < 8; i++) {
      float v0 = ld(in, (size_t)(n * 128 + cb + 2 * i)     * HW + px0 + px, f);
      float v1 = ld(in, (size_t)(n * 128 + cb + 2 * i + 1) * HW + px0 + px, f);
      unsigned h0 = __half_as_ushort(__float2half(v0));
      unsigned h1 = __half_as_ushort(__float2half(v1));
      pk[i] = h0 | (h1 << 16);
    }
    uint4 a, b;
    a.x = pk[0]; a.y = pk[1]; a.z = pk[2]; a.w = pk[3];
    b.x = pk[4]; b.y = pk[5]; b.z = pk[6]; b.w = pk[7];
    *(uint4*)(&lds[px][cb])     = a;
    *(uint4*)(&lds[px][cb + 8]) = b;
  }
  __syncthreads();
  const int px2 = t >> 3;
  const int cg = (t & 7) * 16;
  if (px0 + px2 < HW) {
    uint4 a = *(const uint4*)(&lds[px2][cg]);
    uint4 b = *(const uint4*)(&lds[px2][cg + 8]);
    __half* o = &out[((size_t)n * HW + px0 + px2) * 128 + cg];
    *(uint4*)(o)     = a;
    *(uint4*)(o + 8) = b;
  }
}

// ---------------- weight transpose: [K,N] -> [N,K] ----------------
__global__ __launch_bounds__(256) void tw_kernel(const void* __restrict__ in,
                                                 bf16* __restrict__ out, int K, int N,
                                                 const int* flag) {
  int f = *flag;
  int idx = blockIdx.x * 256 + threadIdx.x;
  if (idx >= K * N) return;
  int n = idx % N, k = idx / N;
  out[n * K + k] = f2b(ld(in, idx, f));
}

// ---------------- S1: logits (MFMA) + softmax (shuffle) + projection ----------------
__global__ __launch_bounds__(256) void logit_proj_kernel(
    const void* __restrict__ query,      // [320000,128] raw
    const void* __restrict__ query_pos,  // [8,40000,3] raw
    const void* __restrict__ l2i,        // [6,4,4] raw (96 elems total!)
    const bf16* __restrict__ wswT,       // [16,128] bf16 (pre-transposed)
    const void* __restrict__ b_sw,       // [16] raw
    float* __restrict__ swG,             // [320000,16]
    float* __restrict__ uG, float* __restrict__ vG, int* __restrict__ cvG,
    const int* flag) {
  const int f32 = *flag;
  const int t = threadIdx.x;
  const int lane = t & 63;
  const int wv = t >> 6;
  const int row0b = blockIdx.x * 256;
  const int row0w = row0b + wv * 64;
  const int quad = lane >> 4, l15 = lane & 15;
  __shared__ float l2iS[96];
  __shared__ float bswS[16];
  if (t < 72) l2iS[t] = ld(l2i, (t / 12) * 16 + (t % 12), f32);  // 6 cams x 12 entries
  if (t >= 96 && t < 112) bswS[t - 96] = ld(b_sw, t - 96, f32);
  short8 bfr[4];
  #pragma unroll
  for (int ks = 0; ks < 4; ks++)
    bfr[ks] = *(const short8*)(&wswT[l15 * 128 + ks * 32 + quad * 8]);
  __syncthreads();
  floatx4 acc[4] = {};
  #pragma unroll
  for (int ks = 0; ks < 4; ks++) {
    #pragma unroll
    for (int mt = 0; mt < 4; mt++) {
      const size_t off = (size_t)(row0w + mt * 16 + l15) * 128 + ks * 32 + quad * 8;
      short8 af;
      if (f32) {
        const float* qf = (const float*)query + off;
        #pragma unroll
        for (int j = 0; j < 8; j++) af[j] = (short)__bfloat16_as_ushort(f2b(qf[j]));
      } else {
        af = *(const short8*)((const bf16*)query + off);
      }
      acc[mt] = __builtin_amdgcn_mfma_f32_16x16x32_bf16(af, bfr[ks], acc[mt], 0, 0, 0);
    }
  }
  const float bias = bswS[l15];
  #pragma unroll
  for (int mt = 0; mt < 4; mt++) {
    #pragma unroll
    for (int r = 0; r < 4; r++) {
      float x = acc[mt][r] + bias;
      float m = fmaxf(x, __shfl_xor(x, 1));
      m = fmaxf(m, __shfl_xor(m, 2));
      float e = expf(x - m);
      float s = e + __shfl_xor(e, 1);
      s += __shfl_xor(s, 2);
      const int rowG = row0w + mt * 16 + quad * 4 + r;
      swG[(size_t)rowG * 16 + l15] = e / s;
    }
  }
  const int row = row0b + t;
  int q = row >> 3, p = row & 7;
  float q0 = ld(query_pos, ((size_t)p * 40000 + q) * 3 + 0, f32);
  float q1 = ld(query_pos, ((size_t)p * 40000 + q) * 3 + 1, f32);
  float q2 = ld(query_pos, ((size_t)p * 40000 + q) * 3 + 2, f32);
  float px = q0 * 100.f - 50.f;
  float py = q1 * 100.f - 50.f;
  float pz = q2 * 8.f - 4.f;
  int cam = 0, found = 0;
  float usel = 0.f, vsel = 0.f;
  for (int n = 0; n < 6; n++) {
    const float* m = &l2iS[n * 12];
    float c0 = m[0] * px + m[1] * py + m[2] * pz + m[3];
    float c1 = m[4] * px + m[5] * py + m[6] * pz + m[7];
    float c2 = m[8] * px + m[9] * py + m[10] * pz + m[11];
    float d = fmaxf(c2, 1e-6f);
    float u = (c0 / d) / 480.f;
    float v = (c1 / d) / 224.f;
    int valid = (c2 > 1e-6f) && (u > 0.f) && (u < 1.f) && (v > 0.f) && (v < 1.f);
    if (valid && !found) { found = 1; cam = n; usel = u; vsel = v; }
  }
  uG[row] = usel; vG[row] = vsel; cvG[row] = cam | (found << 3);
}

// ---------------- S2: gather, one wave per (q,p) row ----------------
__global__ __launch_bounds__(256) void gather_kernel(
    const float* __restrict__ swG, const float* __restrict__ uG,
    const float* __restrict__ vG, const int* __restrict__ cvG,
    const __half* __restrict__ ft, bf16* __restrict__ X) {
  const int t = threadIdx.x;
  const int lane = t & 63;
  const int row = blockIdx.x * 4 + (t >> 6);
  const int lvl = lane >> 4;
  const int l15 = lane & 15;
  float acc[8];
  #pragma unroll
  for (int k = 0; k < 8; k++) acc[k] = 0.f;
  const int cv = __builtin_amdgcn_readfirstlane(cvG[row]);
  if (cv & 8) {
    const float u = u2f(__builtin_amdgcn_readfirstlane(__float_as_uint(uG[row])));
    const float v = u2f(__builtin_amdgcn_readfirstlane(__float_as_uint(vG[row])));
    const int cam = cv & 7;
    const int h = 56 >> lvl;            // 56,28,14,7
    const int w = 120 >> lvl;           // 120,60,30,15
    const int fo4 = (lvl == 0) ? 0 : (lvl == 1) ? 645120 : (lvl == 2) ? 806400 : 846720;
    const int hw16 = h * w * 16;        // uint4 per camera at this level
    const float wl = swG[(size_t)row * 16 + (l15 >> 2) * 4 + lvl];
    float x = u * w - 0.5f, y = v * h - 0.5f;
    float x0f = floorf(x), y0f = floorf(y);
    float wx = x - x0f, wy = y - y0f;
    int x0 = (int)x0f, y0 = (int)y0f;
    int x0c = min(max(x0, 0), w - 1), x1c = min(max(x0 + 1, 0), w - 1);
    int y0c = min(max(y0, 0), h - 1), y1c = min(max(y0 + 1, 0), h - 1);
    float mx0 = (x0 >= 0 && x0 < w) ? wl : 0.f;
    float mx1 = (x0 + 1 < w) ? wl : 0.f;
    float my0 = (y0 >= 0 && y0 < h) ? 1.f : 0.f;
    float my1 = (y0 + 1 < h) ? 1.f : 0.f;
    const float c00 = (1.f - wx) * (1.f - wy) * mx0 * my0;
    const float c10 = wx * (1.f - wy) * mx1 * my0;
    const float c01 = (1.f - wx) * wy * mx0 * my1;
    const float c11 = wx * wy * mx1 * my1;
    const uint4* fb = (const uint4*)ft + fo4 + cam * hw16 + l15;
    const int o00 = (y0c * w + x0c) * 16;
    const int o10 = (y0c * w + x1c) * 16;
    const int o01 = (y1c * w + x0c) * 16;
    const int o11 = (y1c * w + x1c) * 16;
    const uint4 d00 = fb[o00];
    const uint4 d10 = fb[o10];
    const uint4 d01 = fb[o01];
    const uint4 d11 = fb[o11];
    #pragma unroll
    for (int c = 0; c < 4; c++) {
      const uint4& d = (c == 0) ? d00 : (c == 1) ? d10 : (c == 2) ? d01 : d11;
      const float cw = (c == 0) ? c00 : (c == 1) ? c10 : (c == 2) ? c01 : c11;
      const __half2* hp = reinterpret_cast<const __half2*>(&d);
      #pragma unroll
      for (int j = 0; j < 4; j++) {
        acc[2 * j]     += __low2float(hp[j]) * cw;
        acc[2 * j + 1] += __high2float(hp[j]) * cw;
      }
    }
    #pragma unroll
    for (int k = 0; k < 8; k++) {
      acc[k] += __shfl_xor(acc[k], 16);
      acc[k] += __shfl_xor(acc[k], 32);
    }
  }
  if (lane < 16) {
    uint4 o;
    unsigned p0 = (unsigned)(unsigned short)__bfloat16_as_ushort(f2b(acc[0]))
                | ((unsigned)(unsigned short)__bfloat16_as_ushort(f2b(acc[1])) << 16);
    unsigned p1 = (unsigned)(unsigned short)__bfloat16_as_ushort(f2b(acc[2]))
                | ((unsigned)(unsigned short)__bfloat16_as_ushort(f2b(acc[3])) << 16);
    unsigned p2 = (unsigned)(unsigned short)__bfloat16_as_ushort(f2b(acc[4]))
                | ((unsigned)(unsigned short)__bfloat16_as_ushort(f2b(acc[5])) << 16);
    unsigned p3 = (unsigned)(unsigned short)__bfloat16_as_ushort(f2b(acc[6]))
                | ((unsigned)(unsigned short)__bfloat16_as_ushort(f2b(acc[7])) << 16);
    o.x = p0; o.y = p1; o.z = p2; o.w = p3;
    ((uint4*)X)[(size_t)row * 16 + l15] = o;
  }
}

// ---------------- bf16 MFMA GEMM (m97 structure): 128x128 tile, BK=32 ----------------
__global__ __launch_bounds__(256) void gemm_bt(
    const bf16* __restrict__ A, const bf16* __restrict__ Bt, const void* __restrict__ bias,
    bf16* __restrict__ Cd, float* __restrict__ Cf,
    int M, int N, int K, int relu, int trans_out, int nbn, const int* flag) {
  __shared__ bf16 As[128 * 32];
  __shared__ bf16 Bs[128 * 32];
  const int f32 = *flag;
  const int t = threadIdx.x;
  const int lane = t & 63;
  const int wv = t >> 6;
  // XCD-bijective swizzle (m204), then decompose: consecutive swz share bm
  const int nwg = gridDim.x;
  const int lin = blockIdx.x;
  const int q8 = nwg >> 3, r8 = nwg & 7;
  const int xcd = lin & 7, idx8 = lin >> 3;
  const int swz = ((xcd < r8) ? (xcd * (q8 + 1)) : (r8 * (q8 + 1) + (xcd - r8) * q8)) + idx8;
  const int bm = (swz / nbn) * 128;
  const int bn = (swz % nbn) * 128;
  const int wm = (wv >> 1) * 64, wn = (wv & 1) * 64;
  const int quad = lane >> 4, l15 = lane & 15;
  const int srow = lane >> 2;
  const int scol = ((lane & 3) * 8) ^ ((lane >= 32) ? 16 : 0);
  const int c0 = wv * 2, c1 = wv * 2 + 1;
  int ar0 = min(bm + c0 * 16 + srow, M - 1);
  int ar1 = min(bm + c1 * 16 + srow, M - 1);
  const int br0 = bn + c0 * 16 + srow;
  const int br1 = bn + c1 * 16 + srow;
  const bf16* pa0 = A + (size_t)ar0 * K + scol;
  const bf16* pa1 = A + (size_t)ar1 * K + scol;
  const bf16* pb0 = Bt + (size_t)br0 * K + scol;
  const bf16* pb1 = Bt + (size_t)br1 * K + scol;
  bf16* la0 = &As[c0 * 512];
  bf16* la1 = &As[c1 * 512];
  bf16* lb0 = &Bs[c0 * 512];
  bf16* lb1 = &Bs[c1 * 512];
  const int axo = quad * 8 ^ ((l15 & 8) ? 16 : 0);
  floatx4 acc[4][4] = {};
  for (int k0 = 0; k0 < K; k0 += 32) {
    gload16(pa0, la0);
    gload16(pa1, la1);
    gload16(pb0, lb0);
    gload16(pb1, lb1);
    pa0 += 32; pa1 += 32; pb0 += 32; pb1 += 32;
    __syncthreads();
    short8 af[4], bfr[4];
    #pragma unroll
    for (int i = 0; i < 4; i++) {
      af[i]  = *(const short8*)(&As[(wm + i * 16 + l15) * 32 + axo]);
      bfr[i] = *(const short8*)(&Bs[(wn + i * 16 + l15) * 32 + axo]);
    }
    #pragma unroll
    for (int mi = 0; mi < 4; mi++)
      #pragma unroll
      for (int ni = 0; ni < 4; ni++)
        acc[mi][ni] = __builtin_amdgcn_mfma_f32_16x16x32_bf16(af[mi], bfr[ni], acc[mi][ni], 0, 0, 0);
    __syncthreads();
  }
  #pragma unroll
  for (int ni = 0; ni < 4; ni++) {
    const int gn = bn + wn + ni * 16 + l15;
    const float bv = ld(bias, gn, f32);
    #pragma unroll
    for (int mi = 0; mi < 4; mi++) {
      #pragma unroll
      for (int r = 0; r < 4; r++) {
        const int gm = bm + wm + mi * 16 + quad * 4 + r;
        if (gm < M) {
          float v = acc[mi][ni][r] + bv;
          if (relu) v = fmaxf(v, 0.f);
          if (trans_out) Cf[(size_t)gn * M + gm] = v;
          else           Cd[(size_t)gm * N + gn] = f2b(v);
        }
      }
    }
  }
}

// ---------------- pos_emb GEMM: X[q*8+z][e] += MLP(query_pos)[e] ----------------
__global__ __launch_bounds__(256) void gemm_pe(
    const void* __restrict__ query_pos, const void* __restrict__ pe_w1,
    const void* __restrict__ pe_b1, const void* __restrict__ pe_b2,
    const bf16* __restrict__ pw2t, bf16* __restrict__ X, const int* flag) {
  __shared__ bf16 As[64 * 40];    // hidden tile, 64 rows x 32 k
  __shared__ bf16 Bs[128 * 40];   // pw2t tile, 128 n-rows x 32 k
  __shared__ float w1S[256 * 4];  // [k]{w1_0,w1_1,w1_2,b1}, unit-swizzled
  __shared__ float qpS[64 * 3];
  const int f32 = *flag;
  const int t = threadIdx.x;
  const int bm = blockIdx.x * 64;
  const int wv = t >> 6, lane = t & 63;
  const int wm = (wv & 1) * 32, wn = (wv >> 1) * 64;
  const int quad = lane >> 4, l15 = lane & 15;
  const int srow = t >> 2, scol = (t & 3) * 8;
  for (int i = t; i < 1024; i += 256) {
    int k = i >> 2, c = i & 3;
    int ku = k ^ ((k >> 3) & 7);
    w1S[ku * 4 + c] = (c < 3) ? ld(pe_w1, c * 256 + k, f32) : ld(pe_b1, k, f32);
  }
  if (t < 64) {
    int r = bm + t, qq = r >> 3, zz = r & 7;
    #pragma unroll
    for (int i = 0; i < 3; i++)
      qpS[t * 3 + i] = ld(query_pos, ((size_t)zz * 40000 + qq) * 3 + i, f32);
  }
  __syncthreads();
  const float a0 = qpS[srow * 3], a1 = qpS[srow * 3 + 1], a2 = qpS[srow * 3 + 2];
  floatx4 acc[2][4] = {};
  for (int k0 = 0; k0 < 256; k0 += 32) {
    short8 hv;
    #pragma unroll
    for (int j = 0; j < 8; j++) {
      int k = k0 + scol + j;
      int ku = k ^ ((k >> 3) & 7);
      const float* wr = &w1S[ku * 4];
      float h = fmaf(a0, wr[0], fmaf(a1, wr[1], fmaf(a2, wr[2], wr[3])));
      hv[j] = (short)__bfloat16_as_ushort(f2b(fmaxf(h, 0.f)));
    }
    *(short8*)(&As[srow * 40 + scol]) = hv;
    #pragma unroll
    for (int rep = 0; rep < 2; rep++) {
      int linear = rep * 256 + t;
      int brow = linear >> 2, bcol = (linear & 3) * 8;
      *(uint4*)(&Bs[brow * 40 + bcol]) =
          *(const uint4*)(&pw2t[(size_t)brow * 256 + k0 + bcol]);
    }
    __syncthreads();
    short8 af[2], bfr[4];
    #pragma unroll
    for (int mi = 0; mi < 2; mi++)
      af[mi] = *(const short8*)(&As[(wm + mi * 16 + l15) * 40 + quad * 8]);
    #pragma unroll
    for (int ni = 0; ni < 4; ni++)
      bfr[ni] = *(const short8*)(&Bs[(wn + ni * 16 + l15) * 40 + quad * 8]);
    #pragma unroll
    for (int mi = 0; mi < 2; mi++)
      #pragma unroll
      for (int ni = 0; ni < 4; ni++)
        acc[mi][ni] = __builtin_amdgcn_mfma_f32_16x16x32_bf16(af[mi], bfr[ni], acc[mi][ni], 0, 0, 0);
    __syncthreads();
  }
  #pragma unroll
  for (int mi = 0; mi < 2; mi++)
    #pragma unroll
    for (int ni = 0; ni < 4; ni++) {
      int gn = wn + ni * 16 + l15;
      float bv = ld(pe_b2, gn, f32);
      #pragma unroll
      for (int r = 0; r < 4; r++) {
        int gm = bm + wm + mi * 16 + quad * 4 + r;
        size_t off = (size_t)gm * 128 + gn;
        X[off] = f2b(acc[mi][ni][r] + bv + b2f(X[off]));
      }
    }
}

extern "C" void kernel_launch(void* const* d_in, const int* in_sizes, int n_in,
                              void* d_out, int out_size, void* d_ws, size_t ws_size,
                              hipStream_t stream) {
  int* flag = (int*)d_ws;
  bf16* ws = (bf16*)d_ws;
  bf16* wswT = ws + 1024;                // 16x128 bf16 (logit W^T), fits in gap < 5760
  bf16* ft   = ws + 5760;                // 6,854,400 (stored as f16)
  bf16* wt1  = ws + 6860160;             // 512x1024
  bf16* wt2  = ws + 7384448;             // 512x512
  bf16* wt3  = ws + 7646592;             // 512x512
  bf16* wt4  = ws + 7908736;             // 128x512
  bf16* pw2t = ws + 7974272;             // 128x256
  bf16* X    = ws + 8007040;             // 40000x1024
  bf16* Ha   = ws + 48967040;            // 40000x512   (ws total ~139 MB)
  bf16* Hb   = X;                        // alias: X dead after layer-1 GEMM
  // sampling scratch aliased onto Ha (dead until layer-1 GEMM writes it)
  float* swG = (float*)Ha;               // 320000x16 fp32 (10.24M be)
  float* uG  = (float*)(ws + 59207040);  // 320000 fp32
  float* vG  = (float*)(ws + 59847040);  // 320000 fp32
  int*   cvG = (int*)(ws + 60487040);    // 320000 int (ends 61127040 < Ha end)

  detect_kernel<<<1, 64, 0, stream>>>(d_in[4], flag);

  tfeat_kernel<<<dim3(210, 6), 256, 0, stream>>>(d_in[0], (__half*)ft, 6720, flag);
  tfeat_kernel<<<dim3(53, 6), 256, 0, stream>>>(d_in[1], (__half*)(ft + 5160960), 1680, flag);
  tfeat_kernel<<<dim3(14, 6), 256, 0, stream>>>(d_in[2], (__half*)(ft + 6451200), 420, flag);
  tfeat_kernel<<<dim3(4, 6), 256, 0, stream>>>(d_in[3], (__half*)(ft + 6773760), 105, flag);
  tw_kernel<<<2048, 256, 0, stream>>>(d_in[13], wt1, 1024, 512, flag);
  tw_kernel<<<1024, 256, 0, stream>>>(d_in[15], wt2, 512, 512, flag);
  tw_kernel<<<1024, 256, 0, stream>>>(d_in[17], wt3, 512, 512, flag);
  tw_kernel<<<256, 256, 0, stream>>>(d_in[19], wt4, 512, 128, flag);
  tw_kernel<<<128, 256, 0, stream>>>(d_in[11], pw2t, 256, 128, flag);
  tw_kernel<<<8, 256, 0, stream>>>(d_in[7], wswT, 128, 16, flag);

  logit_proj_kernel<<<1250, 256, 0, stream>>>(d_in[4], d_in[5], d_in[6], wswT, d_in[8],
                                              swG, uG, vG, cvG, flag);
  gather_kernel<<<80000, 256, 0, stream>>>(swG, uG, vG, cvG, (const __half*)ft, X);
  gemm_pe<<<5000, 256, 0, stream>>>(d_in[5], d_in[9], d_in[10], d_in[12],
                                    pw2t, X, flag);

  const int nbm = 313;  // ceil(40000/128)
  gemm_bt<<<nbm * 4, 256, 0, stream>>>(X,  wt1, d_in[14], Ha, nullptr, 40000, 512, 1024, 1, 0, 4, flag);
  gemm_bt<<<nbm * 4, 256, 0, stream>>>(Ha, wt2, d_in[16], Hb, nullptr, 40000, 512, 512, 1, 0, 4, flag);
  gemm_bt<<<nbm * 4, 256, 0, stream>>>(Hb, wt3, d_in[18], Ha, nullptr, 40000, 512, 512, 1, 0, 4, flag);
  gemm_bt<<<nbm * 1, 256, 0, stream>>>(Ha, wt4, d_in[20], nullptr, (float*)d_out, 40000, 128, 512, 0, 1, 1, flag);
}

// Round 8
// 701.273 us; speedup vs baseline: 1.8095x; 1.0194x over previous
//
#include <hip/hip_runtime.h>
#include <hip/hip_bf16.h>
#include <hip/hip_fp16.h>

using bf16 = __hip_bfloat16;
typedef __attribute__((ext_vector_type(8))) short short8;
typedef __attribute__((ext_vector_type(4))) float floatx4;

__device__ __forceinline__ float b2f(bf16 x) { return __bfloat162float(x); }
__device__ __forceinline__ bf16  f2b(float x) { return __float2bfloat16(x); }
__device__ __forceinline__ float u2f(unsigned x) { return __uint_as_float(x); }
// dual-dtype raw-input load: fp32 or bf16 depending on runtime flag
__device__ __forceinline__ float ld(const void* p, size_t i, int f32) {
  return f32 ? ((const float*)p)[i] : b2f(((const bf16*)p)[i]);
}
// async global->LDS, 16B per lane; lds dest must be wave-uniform base
__device__ __forceinline__ void gload16(const bf16* g, bf16* l) {
  __builtin_amdgcn_global_load_lds(
      (const __attribute__((address_space(1))) unsigned int*)(g),
      (__attribute__((address_space(3))) unsigned int*)(l), 16, 0, 0);
}

// ---------------- dtype detector ----------------
__global__ void detect_kernel(const void* q, int* flag) {
  if (threadIdx.x == 0) {
    const unsigned short* u = (const unsigned short*)q;
    int f = 0;
    for (int i = 0; i < 128; i++) {
      unsigned e = (u[i] >> 7) & 0xFF;
      if (e >= 141) f = 1;
    }
    *flag = f;
  }
}

// ---------------- feat transpose: (6,128,HW) -> (6,HW,128), f16 out ----------------
__global__ __launch_bounds__(256) void tfeat_kernel(const void* __restrict__ in,
                                                    __half* __restrict__ out, int HW,
                                                    const int* flag) {
  __shared__ unsigned short lds[32][136];   // pad 8 ushort: px stride 272B
  const int f = *flag;
  const int n = blockIdx.y;
  const int px0 = blockIdx.x * 32;
  const int t = threadIdx.x;
  const int px = t & 31;
  const int cb = (t >> 5) * 16;
  if (px0 + px < HW) {
    unsigned pk[8];
    #pragma unroll
    for (int i = 0; i < 8; i++) {
      float v0 = ld(in, (size_t)(n * 128 + cb + 2 * i)     * HW + px0 + px, f);
      float v1 = ld(in, (size_t)(n * 128 + cb + 2 * i + 1) * HW + px0 + px, f);
      unsigned h0 = __half_as_ushort(__float2half(v0));
      unsigned h1 = __half_as_ushort(__float2half(v1));
      pk[i] = h0 | (h1 << 16);
    }
    uint4 a, b;
    a.x = pk[0]; a.y = pk[1]; a.z = pk[2]; a.w = pk[3];
    b.x = pk[4]; b.y = pk[5]; b.z = pk[6]; b.w = pk[7];
    *(uint4*)(&lds[px][cb])     = a;
    *(uint4*)(&lds[px][cb + 8]) = b;
  }
  __syncthreads();
  const int px2 = t >> 3;
  const int cg = (t & 7) * 16;
  if (px0 + px2 < HW) {
    uint4 a = *(const uint4*)(&lds[px2][cg]);
    uint4 b = *(const uint4*)(&lds[px2][cg + 8]);
    __half* o = &out[((size_t)n * HW + px0 + px2) * 128 + cg];
    *(uint4*)(o)     = a;
    *(uint4*)(o + 8) = b;
  }
}

// ---------------- weight transpose: [K,N] -> [N,K] ----------------
__global__ __launch_bounds__(256) void tw_kernel(const void* __restrict__ in,
                                                 bf16* __restrict__ out, int K, int N,
                                                 const int* flag) {
  int f = *flag;
  int idx = blockIdx.x * 256 + threadIdx.x;
  if (idx >= K * N) return;
  int n = idx % N, k = idx / N;
  out[n * K + k] = f2b(ld(in, idx, f));
}

// ---------------- S1: logits (MFMA) + softmax (shuffle) + projection ----------------
__global__ __launch_bounds__(256) void logit_proj_kernel(
    const void* __restrict__ query,      // [320000,128] raw
    const void* __restrict__ query_pos,  // [8,40000,3] raw
    const void* __restrict__ l2i,        // [6,4,4] raw (96 elems total!)
    const bf16* __restrict__ wswT,       // [16,128] bf16 (pre-transposed)
    const void* __restrict__ b_sw,       // [16] raw
    float* __restrict__ swG,             // [320000,16]
    float* __restrict__ uG, float* __restrict__ vG, int* __restrict__ cvG,
    const int* flag) {
  const int f32 = *flag;
  const int t = threadIdx.x;
  const int lane = t & 63;
  const int wv = t >> 6;
  const int row0b = blockIdx.x * 256;
  const int row0w = row0b + wv * 64;
  const int quad = lane >> 4, l15 = lane & 15;
  __shared__ float l2iS[96];
  __shared__ float bswS[16];
  if (t < 72) l2iS[t] = ld(l2i, (t / 12) * 16 + (t % 12), f32);  // 6 cams x 12 entries
  if (t >= 96 && t < 112) bswS[t - 96] = ld(b_sw, t - 96, f32);
  short8 bfr[4];
  #pragma unroll
  for (int ks = 0; ks < 4; ks++)
    bfr[ks] = *(const short8*)(&wswT[l15 * 128 + ks * 32 + quad * 8]);
  __syncthreads();
  floatx4 acc[4] = {};
  #pragma unroll
  for (int ks = 0; ks < 4; ks++) {
    #pragma unroll
    for (int mt = 0; mt < 4; mt++) {
      const size_t off = (size_t)(row0w + mt * 16 + l15) * 128 + ks * 32 + quad * 8;
      short8 af;
      if (f32) {
        const float* qf = (const float*)query + off;
        #pragma unroll
        for (int j = 0; j < 8; j++) af[j] = (short)__bfloat16_as_ushort(f2b(qf[j]));
      } else {
        af = *(const short8*)((const bf16*)query + off);
      }
      acc[mt] = __builtin_amdgcn_mfma_f32_16x16x32_bf16(af, bfr[ks], acc[mt], 0, 0, 0);
    }
  }
  const float bias = bswS[l15];
  #pragma unroll
  for (int mt = 0; mt < 4; mt++) {
    #pragma unroll
    for (int r = 0; r < 4; r++) {
      float x = acc[mt][r] + bias;
      float m = fmaxf(x, __shfl_xor(x, 1));
      m = fmaxf(m, __shfl_xor(m, 2));
      float e = expf(x - m);
      float s = e + __shfl_xor(e, 1);
      s += __shfl_xor(s, 2);
      const int rowG = row0w + mt * 16 + quad * 4 + r;
      swG[(size_t)rowG * 16 + l15] = e / s;
    }
  }
  const int row = row0b + t;
  int q = row >> 3, p = row & 7;
  float q0 = ld(query_pos, ((size_t)p * 40000 + q) * 3 + 0, f32);
  float q1 = ld(query_pos, ((size_t)p * 40000 + q) * 3 + 1, f32);
  float q2 = ld(query_pos, ((size_t)p * 40000 + q) * 3 + 2, f32);
  float px = q0 * 100.f - 50.f;
  float py = q1 * 100.f - 50.f;
  float pz = q2 * 8.f - 4.f;
  int cam = 0, found = 0;
  float usel = 0.f, vsel = 0.f;
  for (int n = 0; n < 6; n++) {
    const float* m = &l2iS[n * 12];
    float c0 = m[0] * px + m[1] * py + m[2] * pz + m[3];
    float c1 = m[4] * px + m[5] * py + m[6] * pz + m[7];
    float c2 = m[8] * px + m[9] * py + m[10] * pz + m[11];
    float d = fmaxf(c2, 1e-6f);
    float u = (c0 / d) / 480.f;
    float v = (c1 / d) / 224.f;
    int valid = (c2 > 1e-6f) && (u > 0.f) && (u < 1.f) && (v > 0.f) && (v < 1.f);
    if (valid && !found) { found = 1; cam = n; usel = u; vsel = v; }
  }
  uG[row] = usel; vG[row] = vsel; cvG[row] = cam | (found << 3);
}

// ---------------- S2: gather, one wave per (q,p) row ----------------
// Level-parallel lanes; packed-f16 accumulation (v_pk_fma_f16) so the
// 32 channel-FMAs are 16 packed ops, cross-level reduce in packed halves.
// f16 accum noise (2^-11) sits below the bf16 output rounding (2^-9).
__global__ __launch_bounds__(256) void gather_kernel(
    const float* __restrict__ swG, const float* __restrict__ uG,
    const float* __restrict__ vG, const int* __restrict__ cvG,
    const __half* __restrict__ ft, bf16* __restrict__ X) {
  const int t = threadIdx.x;
  const int lane = t & 63;
  const int row = blockIdx.x * 4 + (t >> 6);
  const int lvl = lane >> 4;
  const int l15 = lane & 15;
  __half2 acc2[4];
  #pragma unroll
  for (int j = 0; j < 4; j++) acc2[j] = __float2half2_rn(0.f);
  const int cv = __builtin_amdgcn_readfirstlane(cvG[row]);
  if (cv & 8) {
    const float u = u2f(__builtin_amdgcn_readfirstlane(__float_as_uint(uG[row])));
    const float v = u2f(__builtin_amdgcn_readfirstlane(__float_as_uint(vG[row])));
    const int cam = cv & 7;
    const int h = 56 >> lvl;            // 56,28,14,7
    const int w = 120 >> lvl;           // 120,60,30,15
    const int fo4 = (lvl == 0) ? 0 : (lvl == 1) ? 645120 : (lvl == 2) ? 806400 : 846720;
    const int hw16 = h * w * 16;        // uint4 per camera at this level
    const float wl = swG[(size_t)row * 16 + (l15 >> 2) * 4 + lvl];
    float x = u * w - 0.5f, y = v * h - 0.5f;
    float x0f = floorf(x), y0f = floorf(y);
    float wx = x - x0f, wy = y - y0f;
    int x0 = (int)x0f, y0 = (int)y0f;
    int x0c = min(max(x0, 0), w - 1), x1c = min(max(x0 + 1, 0), w - 1);
    int y0c = min(max(y0, 0), h - 1), y1c = min(max(y0 + 1, 0), h - 1);
    // fold softmax weight + OOB masks into separable axis weights
    const float ax0 = (x0 >= 0 && x0 < w) ? (1.f - wx) * wl : 0.f;
    const float ax1 = (x0 + 1 < w) ? wx * wl : 0.f;
    const float wy0 = (y0 >= 0 && y0 < h) ? (1.f - wy) : 0.f;
    const float wy1 = (y0 + 1 < h) ? wy : 0.f;
    const __half2 cw00 = __float2half2_rn(ax0 * wy0);
    const __half2 cw10 = __float2half2_rn(ax1 * wy0);
    const __half2 cw01 = __float2half2_rn(ax0 * wy1);
    const __half2 cw11 = __float2half2_rn(ax1 * wy1);
    const uint4* fb = (const uint4*)ft + fo4 + cam * hw16 + l15;
    const uint4 d00 = fb[(y0c * w + x0c) * 16];
    const uint4 d10 = fb[(y0c * w + x1c) * 16];
    const uint4 d01 = fb[(y1c * w + x0c) * 16];
    const uint4 d11 = fb[(y1c * w + x1c) * 16];
    const __half2* h00 = reinterpret_cast<const __half2*>(&d00);
    const __half2* h10 = reinterpret_cast<const __half2*>(&d10);
    const __half2* h01 = reinterpret_cast<const __half2*>(&d01);
    const __half2* h11 = reinterpret_cast<const __half2*>(&d11);
    #pragma unroll
    for (int j = 0; j < 4; j++) {
      acc2[j] = __hfma2(h00[j], cw00, acc2[j]);
      acc2[j] = __hfma2(h10[j], cw10, acc2[j]);
      acc2[j] = __hfma2(h01[j], cw01, acc2[j]);
      acc2[j] = __hfma2(h11[j], cw11, acc2[j]);
    }
    // cross-level reduce (packed): partners lane^16, lane^32
    #pragma unroll
    for (int j = 0; j < 4; j++) {
      unsigned a = *reinterpret_cast<unsigned*>(&acc2[j]);
      unsigned b = (unsigned)__shfl_xor((int)a, 16);
      acc2[j] = __hadd2(acc2[j], *reinterpret_cast<__half2*>(&b));
      a = *reinterpret_cast<unsigned*>(&acc2[j]);
      b = (unsigned)__shfl_xor((int)a, 32);
      acc2[j] = __hadd2(acc2[j], *reinterpret_cast<__half2*>(&b));
    }
  }
  if (lane < 16) {
    uint4 o;
    unsigned* po = reinterpret_cast<unsigned*>(&o);
    #pragma unroll
    for (int j = 0; j < 4; j++) {
      float lo = __low2float(acc2[j]);
      float hi = __high2float(acc2[j]);
      po[j] = (unsigned)(unsigned short)__bfloat16_as_ushort(f2b(lo))
            | ((unsigned)(unsigned short)__bfloat16_as_ushort(f2b(hi)) << 16);
    }
    ((uint4*)X)[(size_t)row * 16 + l15] = o;
  }
}

// ---------------- bf16 MFMA GEMM (m97 structure): 128x128 tile, BK=32 ----------------
__global__ __launch_bounds__(256) void gemm_bt(
    const bf16* __restrict__ A, const bf16* __restrict__ Bt, const void* __restrict__ bias,
    bf16* __restrict__ Cd, float* __restrict__ Cf,
    int M, int N, int K, int relu, int trans_out, int nbn, const int* flag) {
  __shared__ bf16 As[128 * 32];
  __shared__ bf16 Bs[128 * 32];
  const int f32 = *flag;
  const int t = threadIdx.x;
  const int lane = t & 63;
  const int wv = t >> 6;
  // XCD-bijective swizzle (m204), then decompose: consecutive swz share bm
  const int nwg = gridDim.x;
  const int lin = blockIdx.x;
  const int q8 = nwg >> 3, r8 = nwg & 7;
  const int xcd = lin & 7, idx8 = lin >> 3;
  const int swz = ((xcd < r8) ? (xcd * (q8 + 1)) : (r8 * (q8 + 1) + (xcd - r8) * q8)) + idx8;
  const int bm = (swz / nbn) * 128;
  const int bn = (swz % nbn) * 128;
  const int wm = (wv >> 1) * 64, wn = (wv & 1) * 64;
  const int quad = lane >> 4, l15 = lane & 15;
  const int srow = lane >> 2;
  const int scol = ((lane & 3) * 8) ^ ((lane >= 32) ? 16 : 0);
  const int c0 = wv * 2, c1 = wv * 2 + 1;
  int ar0 = min(bm + c0 * 16 + srow, M - 1);
  int ar1 = min(bm + c1 * 16 + srow, M - 1);
  const int br0 = bn + c0 * 16 + srow;
  const int br1 = bn + c1 * 16 + srow;
  const bf16* pa0 = A + (size_t)ar0 * K + scol;
  const bf16* pa1 = A + (size_t)ar1 * K + scol;
  const bf16* pb0 = Bt + (size_t)br0 * K + scol;
  const bf16* pb1 = Bt + (size_t)br1 * K + scol;
  bf16* la0 = &As[c0 * 512];
  bf16* la1 = &As[c1 * 512];
  bf16* lb0 = &Bs[c0 * 512];
  bf16* lb1 = &Bs[c1 * 512];
  const int axo = quad * 8 ^ ((l15 & 8) ? 16 : 0);
  floatx4 acc[4][4] = {};
  for (int k0 = 0; k0 < K; k0 += 32) {
    gload16(pa0, la0);
    gload16(pa1, la1);
    gload16(pb0, lb0);
    gload16(pb1, lb1);
    pa0 += 32; pa1 += 32; pb0 += 32; pb1 += 32;
    __syncthreads();
    short8 af[4], bfr[4];
    #pragma unroll
    for (int i = 0; i < 4; i++) {
      af[i]  = *(const short8*)(&As[(wm + i * 16 + l15) * 32 + axo]);
      bfr[i] = *(const short8*)(&Bs[(wn + i * 16 + l15) * 32 + axo]);
    }
    #pragma unroll
    for (int mi = 0; mi < 4; mi++)
      #pragma unroll
      for (int ni = 0; ni < 4; ni++)
        acc[mi][ni] = __builtin_amdgcn_mfma_f32_16x16x32_bf16(af[mi], bfr[ni], acc[mi][ni], 0, 0, 0);
    __syncthreads();
  }
  #pragma unroll
  for (int ni = 0; ni < 4; ni++) {
    const int gn = bn + wn + ni * 16 + l15;
    const float bv = ld(bias, gn, f32);
    #pragma unroll
    for (int mi = 0; mi < 4; mi++) {
      #pragma unroll
      for (int r = 0; r < 4; r++) {
        const int gm = bm + wm + mi * 16 + quad * 4 + r;
        if (gm < M) {
          float v = acc[mi][ni][r] + bv;
          if (relu) v = fmaxf(v, 0.f);
          if (trans_out) Cf[(size_t)gn * M + gm] = v;
          else           Cd[(size_t)gm * N + gn] = f2b(v);
        }
      }
    }
  }
}

// ---------------- pos_emb GEMM: X[q*8+z][e] += MLP(query_pos)[e] ----------------
__global__ __launch_bounds__(256) void gemm_pe(
    const void* __restrict__ query_pos, const void* __restrict__ pe_w1,
    const void* __restrict__ pe_b1, const void* __restrict__ pe_b2,
    const bf16* __restrict__ pw2t, bf16* __restrict__ X, const int* flag) {
  __shared__ bf16 As[64 * 40];    // hidden tile, 64 rows x 32 k
  __shared__ bf16 Bs[128 * 40];   // pw2t tile, 128 n-rows x 32 k
  __shared__ float w1S[256 * 4];  // [k]{w1_0,w1_1,w1_2,b1}, unit-swizzled
  __shared__ float qpS[64 * 3];
  const int f32 = *flag;
  const int t = threadIdx.x;
  const int bm = blockIdx.x * 64;
  const int wv = t >> 6, lane = t & 63;
  const int wm = (wv & 1) * 32, wn = (wv >> 1) * 64;
  const int quad = lane >> 4, l15 = lane & 15;
  const int srow = t >> 2, scol = (t & 3) * 8;
  for (int i = t; i < 1024; i += 256) {
    int k = i >> 2, c = i & 3;
    int ku = k ^ ((k >> 3) & 7);
    w1S[ku * 4 + c] = (c < 3) ? ld(pe_w1, c * 256 + k, f32) : ld(pe_b1, k, f32);
  }
  if (t < 64) {
    int r = bm + t, qq = r >> 3, zz = r & 7;
    #pragma unroll
    for (int i = 0; i < 3; i++)
      qpS[t * 3 + i] = ld(query_pos, ((size_t)zz * 40000 + qq) * 3 + i, f32);
  }
  __syncthreads();
  const float a0 = qpS[srow * 3], a1 = qpS[srow * 3 + 1], a2 = qpS[srow * 3 + 2];
  floatx4 acc[2][4] = {};
  for (int k0 = 0; k0 < 256; k0 += 32) {
    short8 hv;
    #pragma unroll
    for (int j = 0; j < 8; j++) {
      int k = k0 + scol + j;
      int ku = k ^ ((k >> 3) & 7);
      const float* wr = &w1S[ku * 4];
      float h = fmaf(a0, wr[0], fmaf(a1, wr[1], fmaf(a2, wr[2], wr[3])));
      hv[j] = (short)__bfloat16_as_ushort(f2b(fmaxf(h, 0.f)));
    }
    *(short8*)(&As[srow * 40 + scol]) = hv;
    #pragma unroll
    for (int rep = 0; rep < 2; rep++) {
      int linear = rep * 256 + t;
      int brow = linear >> 2, bcol = (linear & 3) * 8;
      *(uint4*)(&Bs[brow * 40 + bcol]) =
          *(const uint4*)(&pw2t[(size_t)brow * 256 + k0 + bcol]);
    }
    __syncthreads();
    short8 af[2], bfr[4];
    #pragma unroll
    for (int mi = 0; mi < 2; mi++)
      af[mi] = *(const short8*)(&As[(wm + mi * 16 + l15) * 40 + quad * 8]);
    #pragma unroll
    for (int ni = 0; ni < 4; ni++)
      bfr[ni] = *(const short8*)(&Bs[(wn + ni * 16 + l15) * 40 + quad * 8]);
    #pragma unroll
    for (int mi = 0; mi < 2; mi++)
      #pragma unroll
      for (int ni = 0; ni < 4; ni++)
        acc[mi][ni] = __builtin_amdgcn_mfma_f32_16x16x32_bf16(af[mi], bfr[ni], acc[mi][ni], 0, 0, 0);
    __syncthreads();
  }
  #pragma unroll
  for (int mi = 0; mi < 2; mi++)
    #pragma unroll
    for (int ni = 0; ni < 4; ni++) {
      int gn = wn + ni * 16 + l15;
      float bv = ld(pe_b2, gn, f32);
      #pragma unroll
      for (int r = 0; r < 4; r++) {
        int gm = bm + wm + mi * 16 + quad * 4 + r;
        size_t off = (size_t)gm * 128 + gn;
        X[off] = f2b(acc[mi][ni][r] + bv + b2f(X[off]));
      }
    }
}

extern "C" void kernel_launch(void* const* d_in, const int* in_sizes, int n_in,
                              void* d_out, int out_size, void* d_ws, size_t ws_size,
                              hipStream_t stream) {
  int* flag = (int*)d_ws;
  bf16* ws = (bf16*)d_ws;
  bf16* wswT = ws + 1024;                // 16x128 bf16 (logit W^T), fits in gap < 5760
  bf16* ft   = ws + 5760;                // 6,854,400 (stored as f16)
  bf16* wt1  = ws + 6860160;             // 512x1024
  bf16* wt2  = ws + 7384448;             // 512x512
  bf16* wt3  = ws + 7646592;             // 512x512
  bf16* wt4  = ws + 7908736;             // 128x512
  bf16* pw2t = ws + 7974272;             // 128x256
  bf16* X    = ws + 8007040;             // 40000x1024
  bf16* Ha   = ws + 48967040;            // 40000x512   (ws total ~139 MB)
  bf16* Hb   = X;                        // alias: X dead after layer-1 GEMM
  // sampling scratch aliased onto Ha (dead until layer-1 GEMM writes it)
  float* swG = (float*)Ha;               // 320000x16 fp32 (10.24M be)
  float* uG  = (float*)(ws + 59207040);  // 320000 fp32
  float* vG  = (float*)(ws + 59847040);  // 320000 fp32
  int*   cvG = (int*)(ws + 60487040);    // 320000 int (ends 61127040 < Ha end)

  detect_kernel<<<1, 64, 0, stream>>>(d_in[4], flag);

  tfeat_kernel<<<dim3(210, 6), 256, 0, stream>>>(d_in[0], (__half*)ft, 6720, flag);
  tfeat_kernel<<<dim3(53, 6), 256, 0, stream>>>(d_in[1], (__half*)(ft + 5160960), 1680, flag);
  tfeat_kernel<<<dim3(14, 6), 256, 0, stream>>>(d_in[2], (__half*)(ft + 6451200), 420, flag);
  tfeat_kernel<<<dim3(4, 6), 256, 0, stream>>>(d_in[3], (__half*)(ft + 6773760), 105, flag);
  tw_kernel<<<2048, 256, 0, stream>>>(d_in[13], wt1, 1024, 512, flag);
  tw_kernel<<<1024, 256, 0, stream>>>(d_in[15], wt2, 512, 512, flag);
  tw_kernel<<<1024, 256, 0, stream>>>(d_in[17], wt3, 512, 512, flag);
  tw_kernel<<<256, 256, 0, stream>>>(d_in[19], wt4, 512, 128, flag);
  tw_kernel<<<128, 256, 0, stream>>>(d_in[11], pw2t, 256, 128, flag);
  tw_kernel<<<8, 256, 0, stream>>>(d_in[7], wswT, 128, 16, flag);

  logit_proj_kernel<<<1250, 256, 0, stream>>>(d_in[4], d_in[5], d_in[6], wswT, d_in[8],
                                              swG, uG, vG, cvG, flag);
  gather_kernel<<<80000, 256, 0, stream>>>(swG, uG, vG, cvG, (const __half*)ft, X);
  gemm_pe<<<5000, 256, 0, stream>>>(d_in[5], d_in[9], d_in[10], d_in[12],
                                    pw2t, X, flag);

  const int nbm = 313;  // ceil(40000/128)
  gemm_bt<<<nbm * 4, 256, 0, stream>>>(X,  wt1, d_in[14], Ha, nullptr, 40000, 512, 1024, 1, 0, 4, flag);
  gemm_bt<<<nbm * 4, 256, 0, stream>>>(Ha, wt2, d_in[16], Hb, nullptr, 40000, 512, 512, 1, 0, 4, flag);
  gemm_bt<<<nbm * 4, 256, 0, stream>>>(Hb, wt3, d_in[18], Ha, nullptr, 40000, 512, 512, 1, 0, 4, flag);
  gemm_bt<<<nbm * 1, 256, 0, stream>>>(Ha, wt4, d_in[20], nullptr, (float*)d_out, 40000, 128, 512, 0, 1, 1, flag);
}

// Round 9
// 690.822 us; speedup vs baseline: 1.8368x; 1.0151x over previous
//
#include <hip/hip_runtime.h>
#include <hip/hip_bf16.h>
#include <hip/hip_fp16.h>

using bf16 = __hip_bfloat16;
typedef __attribute__((ext_vector_type(8))) short short8;
typedef __attribute__((ext_vector_type(4))) float floatx4;

__device__ __forceinline__ float b2f(bf16 x) { return __bfloat162float(x); }
__device__ __forceinline__ bf16  f2b(float x) { return __float2bfloat16(x); }
__device__ __forceinline__ float u2f(unsigned x) { return __uint_as_float(x); }
// dual-dtype raw-input load: fp32 or bf16 depending on runtime flag
__device__ __forceinline__ float ld(const void* p, size_t i, int f32) {
  return f32 ? ((const float*)p)[i] : b2f(((const bf16*)p)[i]);
}
// async global->LDS, 16B per lane; lds dest must be wave-uniform base
__device__ __forceinline__ void gload16(const bf16* g, bf16* l) {
  __builtin_amdgcn_global_load_lds(
      (const __attribute__((address_space(1))) unsigned int*)(g),
      (__attribute__((address_space(3))) unsigned int*)(l), 16, 0, 0);
}

// ---------------- dtype detector ----------------
__global__ void detect_kernel(const void* q, int* flag) {
  if (threadIdx.x == 0) {
    const unsigned short* u = (const unsigned short*)q;
    int f = 0;
    for (int i = 0; i < 128; i++) {
      unsigned e = (u[i] >> 7) & 0xFF;
      if (e >= 141) f = 1;
    }
    *flag = f;
  }
}

// ---------------- feat transpose: (6,128,HW) -> (6,HW,128), f16 out ----------------
__global__ __launch_bounds__(256) void tfeat_kernel(const void* __restrict__ in,
                                                    __half* __restrict__ out, int HW,
                                                    const int* flag) {
  __shared__ unsigned short lds[32][136];   // pad 8 ushort: px stride 272B
  const int f = *flag;
  const int n = blockIdx.y;
  const int px0 = blockIdx.x * 32;
  const int t = threadIdx.x;
  const int px = t & 31;
  const int cb = (t >> 5) * 16;
  if (px0 + px < HW) {
    unsigned pk[8];
    #pragma unroll
    for (int i = 0; i < 8; i++) {
      float v0 = ld(in, (size_t)(n * 128 + cb + 2 * i)     * HW + px0 + px, f);
      float v1 = ld(in, (size_t)(n * 128 + cb + 2 * i + 1) * HW + px0 + px, f);
      unsigned h0 = __half_as_ushort(__float2half(v0));
      unsigned h1 = __half_as_ushort(__float2half(v1));
      pk[i] = h0 | (h1 << 16);
    }
    uint4 a, b;
    a.x = pk[0]; a.y = pk[1]; a.z = pk[2]; a.w = pk[3];
    b.x = pk[4]; b.y = pk[5]; b.z = pk[6]; b.w = pk[7];
    *(uint4*)(&lds[px][cb])     = a;
    *(uint4*)(&lds[px][cb + 8]) = b;
  }
  __syncthreads();
  const int px2 = t >> 3;
  const int cg = (t & 7) * 16;
  if (px0 + px2 < HW) {
    uint4 a = *(const uint4*)(&lds[px2][cg]);
    uint4 b = *(const uint4*)(&lds[px2][cg + 8]);
    __half* o = &out[((size_t)n * HW + px0 + px2) * 128 + cg];
    *(uint4*)(o)     = a;
    *(uint4*)(o + 8) = b;
  }
}

// ---------------- weight transpose: [K,N] -> [N,K] ----------------
__global__ __launch_bounds__(256) void tw_kernel(const void* __restrict__ in,
                                                 bf16* __restrict__ out, int K, int N,
                                                 const int* flag) {
  int f = *flag;
  int idx = blockIdx.x * 256 + threadIdx.x;
  if (idx >= K * N) return;
  int n = idx % N, k = idx / N;
  out[n * K + k] = f2b(ld(in, idx, f));
}

// ---------------- S1: logits (MFMA) + softmax (shuffle) + projection ----------------
__global__ __launch_bounds__(256) void logit_proj_kernel(
    const void* __restrict__ query,      // [320000,128] raw
    const void* __restrict__ query_pos,  // [8,40000,3] raw
    const void* __restrict__ l2i,        // [6,4,4] raw (96 elems total!)
    const bf16* __restrict__ wswT,       // [16,128] bf16 (pre-transposed)
    const void* __restrict__ b_sw,       // [16] raw
    float* __restrict__ swG,             // [320000,16]
    float* __restrict__ uG, float* __restrict__ vG, int* __restrict__ cvG,
    const int* flag) {
  const int f32 = *flag;
  const int t = threadIdx.x;
  const int lane = t & 63;
  const int wv = t >> 6;
  const int row0b = blockIdx.x * 256;
  const int row0w = row0b + wv * 64;
  const int quad = lane >> 4, l15 = lane & 15;
  __shared__ float l2iS[96];
  __shared__ float bswS[16];
  if (t < 72) l2iS[t] = ld(l2i, (t / 12) * 16 + (t % 12), f32);  // 6 cams x 12 entries
  if (t >= 96 && t < 112) bswS[t - 96] = ld(b_sw, t - 96, f32);
  short8 bfr[4];
  #pragma unroll
  for (int ks = 0; ks < 4; ks++)
    bfr[ks] = *(const short8*)(&wswT[l15 * 128 + ks * 32 + quad * 8]);
  __syncthreads();
  floatx4 acc[4] = {};
  #pragma unroll
  for (int ks = 0; ks < 4; ks++) {
    #pragma unroll
    for (int mt = 0; mt < 4; mt++) {
      const size_t off = (size_t)(row0w + mt * 16 + l15) * 128 + ks * 32 + quad * 8;
      short8 af;
      if (f32) {
        const float* qf = (const float*)query + off;
        #pragma unroll
        for (int j = 0; j < 8; j++) af[j] = (short)__bfloat16_as_ushort(f2b(qf[j]));
      } else {
        af = *(const short8*)((const bf16*)query + off);
      }
      acc[mt] = __builtin_amdgcn_mfma_f32_16x16x32_bf16(af, bfr[ks], acc[mt], 0, 0, 0);
    }
  }
  const float bias = bswS[l15];
  #pragma unroll
  for (int mt = 0; mt < 4; mt++) {
    #pragma unroll
    for (int r = 0; r < 4; r++) {
      float x = acc[mt][r] + bias;
      float m = fmaxf(x, __shfl_xor(x, 1));
      m = fmaxf(m, __shfl_xor(m, 2));
      float e = expf(x - m);
      float s = e + __shfl_xor(e, 1);
      s += __shfl_xor(s, 2);
      const int rowG = row0w + mt * 16 + quad * 4 + r;
      swG[(size_t)rowG * 16 + l15] = e / s;
    }
  }
  const int row = row0b + t;
  int q = row >> 3, p = row & 7;
  float q0 = ld(query_pos, ((size_t)p * 40000 + q) * 3 + 0, f32);
  float q1 = ld(query_pos, ((size_t)p * 40000 + q) * 3 + 1, f32);
  float q2 = ld(query_pos, ((size_t)p * 40000 + q) * 3 + 2, f32);
  float px = q0 * 100.f - 50.f;
  float py = q1 * 100.f - 50.f;
  float pz = q2 * 8.f - 4.f;
  int cam = 0, found = 0;
  float usel = 0.f, vsel = 0.f;
  for (int n = 0; n < 6; n++) {
    const float* m = &l2iS[n * 12];
    float c0 = m[0] * px + m[1] * py + m[2] * pz + m[3];
    float c1 = m[4] * px + m[5] * py + m[6] * pz + m[7];
    float c2 = m[8] * px + m[9] * py + m[10] * pz + m[11];
    float d = fmaxf(c2, 1e-6f);
    float u = (c0 / d) / 480.f;
    float v = (c1 / d) / 224.f;
    int valid = (c2 > 1e-6f) && (u > 0.f) && (u < 1.f) && (v > 0.f) && (v < 1.f);
    if (valid && !found) { found = 1; cam = n; usel = u; vsel = v; }
  }
  uG[row] = usel; vG[row] = vsel; cvG[row] = cam | (found << 3);
}

// ---------------- S2: gather, one wave per (q,p) row ----------------
__global__ __launch_bounds__(256) void gather_kernel(
    const float* __restrict__ swG, const float* __restrict__ uG,
    const float* __restrict__ vG, const int* __restrict__ cvG,
    const __half* __restrict__ ft, bf16* __restrict__ X) {
  const int t = threadIdx.x;
  const int lane = t & 63;
  const int row = blockIdx.x * 4 + (t >> 6);
  const int lvl = lane >> 4;
  const int l15 = lane & 15;
  __half2 acc2[4];
  #pragma unroll
  for (int j = 0; j < 4; j++) acc2[j] = __float2half2_rn(0.f);
  const int cv = __builtin_amdgcn_readfirstlane(cvG[row]);
  if (cv & 8) {
    const float u = u2f(__builtin_amdgcn_readfirstlane(__float_as_uint(uG[row])));
    const float v = u2f(__builtin_amdgcn_readfirstlane(__float_as_uint(vG[row])));
    const int cam = cv & 7;
    const int h = 56 >> lvl;            // 56,28,14,7
    const int w = 120 >> lvl;           // 120,60,30,15
    const int fo4 = (lvl == 0) ? 0 : (lvl == 1) ? 645120 : (lvl == 2) ? 806400 : 846720;
    const int hw16 = h * w * 16;        // uint4 per camera at this level
    const float wl = swG[(size_t)row * 16 + (l15 >> 2) * 4 + lvl];
    float x = u * w - 0.5f, y = v * h - 0.5f;
    float x0f = floorf(x), y0f = floorf(y);
    float wx = x - x0f, wy = y - y0f;
    int x0 = (int)x0f, y0 = (int)y0f;
    int x0c = min(max(x0, 0), w - 1), x1c = min(max(x0 + 1, 0), w - 1);
    int y0c = min(max(y0, 0), h - 1), y1c = min(max(y0 + 1, 0), h - 1);
    // fold softmax weight + OOB masks into separable axis weights
    const float ax0 = (x0 >= 0 && x0 < w) ? (1.f - wx) * wl : 0.f;
    const float ax1 = (x0 + 1 < w) ? wx * wl : 0.f;
    const float wy0 = (y0 >= 0 && y0 < h) ? (1.f - wy) : 0.f;
    const float wy1 = (y0 + 1 < h) ? wy : 0.f;
    const __half2 cw00 = __float2half2_rn(ax0 * wy0);
    const __half2 cw10 = __float2half2_rn(ax1 * wy0);
    const __half2 cw01 = __float2half2_rn(ax0 * wy1);
    const __half2 cw11 = __float2half2_rn(ax1 * wy1);
    const uint4* fb = (const uint4*)ft + fo4 + cam * hw16 + l15;
    const uint4 d00 = fb[(y0c * w + x0c) * 16];
    const uint4 d10 = fb[(y0c * w + x1c) * 16];
    const uint4 d01 = fb[(y1c * w + x0c) * 16];
    const uint4 d11 = fb[(y1c * w + x1c) * 16];
    const __half2* h00 = reinterpret_cast<const __half2*>(&d00);
    const __half2* h10 = reinterpret_cast<const __half2*>(&d10);
    const __half2* h01 = reinterpret_cast<const __half2*>(&d01);
    const __half2* h11 = reinterpret_cast<const __half2*>(&d11);
    #pragma unroll
    for (int j = 0; j < 4; j++) {
      acc2[j] = __hfma2(h00[j], cw00, acc2[j]);
      acc2[j] = __hfma2(h10[j], cw10, acc2[j]);
      acc2[j] = __hfma2(h01[j], cw01, acc2[j]);
      acc2[j] = __hfma2(h11[j], cw11, acc2[j]);
    }
    // cross-level reduce (packed): partners lane^16, lane^32
    #pragma unroll
    for (int j = 0; j < 4; j++) {
      unsigned a = *reinterpret_cast<unsigned*>(&acc2[j]);
      unsigned b = (unsigned)__shfl_xor((int)a, 16);
      acc2[j] = __hadd2(acc2[j], *reinterpret_cast<__half2*>(&b));
      a = *reinterpret_cast<unsigned*>(&acc2[j]);
      b = (unsigned)__shfl_xor((int)a, 32);
      acc2[j] = __hadd2(acc2[j], *reinterpret_cast<__half2*>(&b));
    }
  }
  if (lane < 16) {
    uint4 o;
    unsigned* po = reinterpret_cast<unsigned*>(&o);
    #pragma unroll
    for (int j = 0; j < 4; j++) {
      float lo = __low2float(acc2[j]);
      float hi = __high2float(acc2[j]);
      po[j] = (unsigned)(unsigned short)__bfloat16_as_ushort(f2b(lo))
            | ((unsigned)(unsigned short)__bfloat16_as_ushort(f2b(hi)) << 16);
    }
    ((uint4*)X)[(size_t)row * 16 + l15] = o;
  }
}

// ---------------- bf16 MFMA GEMM (m97 structure): 128x128 tile, BK=32 ----------------
__global__ __launch_bounds__(256) void gemm_bt(
    const bf16* __restrict__ A, const bf16* __restrict__ Bt, const void* __restrict__ bias,
    bf16* __restrict__ Cd, float* __restrict__ Cf,
    int M, int N, int K, int relu, int trans_out, int nbn, const int* flag) {
  __shared__ bf16 As[128 * 32];
  __shared__ bf16 Bs[128 * 32];
  const int f32 = *flag;
  const int t = threadIdx.x;
  const int lane = t & 63;
  const int wv = t >> 6;
  // XCD-bijective swizzle (m204), then decompose: consecutive swz share bm
  const int nwg = gridDim.x;
  const int lin = blockIdx.x;
  const int q8 = nwg >> 3, r8 = nwg & 7;
  const int xcd = lin & 7, idx8 = lin >> 3;
  const int swz = ((xcd < r8) ? (xcd * (q8 + 1)) : (r8 * (q8 + 1) + (xcd - r8) * q8)) + idx8;
  const int bm = (swz / nbn) * 128;
  const int bn = (swz % nbn) * 128;
  const int wm = (wv >> 1) * 64, wn = (wv & 1) * 64;
  const int quad = lane >> 4, l15 = lane & 15;
  const int srow = lane >> 2;
  const int scol = ((lane & 3) * 8) ^ ((lane >= 32) ? 16 : 0);
  const int c0 = wv * 2, c1 = wv * 2 + 1;
  int ar0 = min(bm + c0 * 16 + srow, M - 1);
  int ar1 = min(bm + c1 * 16 + srow, M - 1);
  const int br0 = bn + c0 * 16 + srow;
  const int br1 = bn + c1 * 16 + srow;
  const bf16* pa0 = A + (size_t)ar0 * K + scol;
  const bf16* pa1 = A + (size_t)ar1 * K + scol;
  const bf16* pb0 = Bt + (size_t)br0 * K + scol;
  const bf16* pb1 = Bt + (size_t)br1 * K + scol;
  bf16* la0 = &As[c0 * 512];
  bf16* la1 = &As[c1 * 512];
  bf16* lb0 = &Bs[c0 * 512];
  bf16* lb1 = &Bs[c1 * 512];
  const int axo = quad * 8 ^ ((l15 & 8) ? 16 : 0);
  floatx4 acc[4][4] = {};
  for (int k0 = 0; k0 < K; k0 += 32) {
    gload16(pa0, la0);
    gload16(pa1, la1);
    gload16(pb0, lb0);
    gload16(pb1, lb1);
    pa0 += 32; pa1 += 32; pb0 += 32; pb1 += 32;
    __syncthreads();
    short8 af[4], bfr[4];
    #pragma unroll
    for (int i = 0; i < 4; i++) {
      af[i]  = *(const short8*)(&As[(wm + i * 16 + l15) * 32 + axo]);
      bfr[i] = *(const short8*)(&Bs[(wn + i * 16 + l15) * 32 + axo]);
    }
    #pragma unroll
    for (int mi = 0; mi < 4; mi++)
      #pragma unroll
      for (int ni = 0; ni < 4; ni++)
        acc[mi][ni] = __builtin_amdgcn_mfma_f32_16x16x32_bf16(af[mi], bfr[ni], acc[mi][ni], 0, 0, 0);
    __syncthreads();
  }
  #pragma unroll
  for (int ni = 0; ni < 4; ni++) {
    const int gn = bn + wn + ni * 16 + l15;
    const float bv = ld(bias, gn, f32);
    #pragma unroll
    for (int mi = 0; mi < 4; mi++) {
      #pragma unroll
      for (int r = 0; r < 4; r++) {
        const int gm = bm + wm + mi * 16 + quad * 4 + r;
        if (gm < M) {
          float v = acc[mi][ni][r] + bv;
          if (relu) v = fmaxf(v, 0.f);
          if (trans_out) Cf[(size_t)gn * M + gm] = v;
          else           Cd[(size_t)gm * N + gn] = f2b(v);
        }
      }
    }
  }
}

// ---------------- pos_emb GEMM: X[q*8+z][e] += MLP(query_pos)[e] ----------------
// One block = 64 rows x full N=128. LDS carved from one buffer so the
// epilogue can reuse the (dead) staging space: acc dumped to a [64][136]
// bf16 tile, then 4 fully-coalesced uint4 RMWs of X per thread
// (scalar 2B VMEM ops: 64 -> 8 per thread).
__global__ __launch_bounds__(256) void gemm_pe(
    const void* __restrict__ query_pos, const void* __restrict__ pe_w1,
    const void* __restrict__ pe_b1, const void* __restrict__ pe_b2,
    const bf16* __restrict__ pw2t, bf16* __restrict__ X, const int* flag) {
  __shared__ char smemB[20224];
  bf16* As = (bf16*)smemB;                     // [64*40]   5120 B
  bf16* Bs = (bf16*)(smemB + 5120);            // [128*40] 10240 B
  float* w1S = (float*)(smemB + 15360);        // [256*4]   4096 B
  float* qpS = (float*)(smemB + 19456);        // [64*3]     768 B
  unsigned short* epi = (unsigned short*)smemB; // [64][136] 17408 B (epilogue reuse)
  const int f32 = *flag;
  const int t = threadIdx.x;
  const int bm = blockIdx.x * 64;
  const int wv = t >> 6, lane = t & 63;
  const int wm = (wv & 1) * 32, wn = (wv >> 1) * 64;
  const int quad = lane >> 4, l15 = lane & 15;
  const int srow = t >> 2, scol = (t & 3) * 8;
  for (int i = t; i < 1024; i += 256) {
    int k = i >> 2, c = i & 3;
    int ku = k ^ ((k >> 3) & 7);
    w1S[ku * 4 + c] = (c < 3) ? ld(pe_w1, c * 256 + k, f32) : ld(pe_b1, k, f32);
  }
  if (t < 64) {
    int r = bm + t, qq = r >> 3, zz = r & 7;
    #pragma unroll
    for (int i = 0; i < 3; i++)
      qpS[t * 3 + i] = ld(query_pos, ((size_t)zz * 40000 + qq) * 3 + i, f32);
  }
  __syncthreads();
  const float a0 = qpS[srow * 3], a1 = qpS[srow * 3 + 1], a2 = qpS[srow * 3 + 2];
  floatx4 acc[2][4] = {};
  for (int k0 = 0; k0 < 256; k0 += 32) {
    short8 hv;
    #pragma unroll
    for (int j = 0; j < 8; j++) {
      int k = k0 + scol + j;
      int ku = k ^ ((k >> 3) & 7);
      const float* wr = &w1S[ku * 4];
      float h = fmaf(a0, wr[0], fmaf(a1, wr[1], fmaf(a2, wr[2], wr[3])));
      hv[j] = (short)__bfloat16_as_ushort(f2b(fmaxf(h, 0.f)));
    }
    *(short8*)(&As[srow * 40 + scol]) = hv;
    #pragma unroll
    for (int rep = 0; rep < 2; rep++) {
      int linear = rep * 256 + t;
      int brow = linear >> 2, bcol = (linear & 3) * 8;
      *(uint4*)(&Bs[brow * 40 + bcol]) =
          *(const uint4*)(&pw2t[(size_t)brow * 256 + k0 + bcol]);
    }
    __syncthreads();
    short8 af[2], bfr[4];
    #pragma unroll
    for (int mi = 0; mi < 2; mi++)
      af[mi] = *(const short8*)(&As[(wm + mi * 16 + l15) * 40 + quad * 8]);
    #pragma unroll
    for (int ni = 0; ni < 4; ni++)
      bfr[ni] = *(const short8*)(&Bs[(wn + ni * 16 + l15) * 40 + quad * 8]);
    #pragma unroll
    for (int mi = 0; mi < 2; mi++)
      #pragma unroll
      for (int ni = 0; ni < 4; ni++)
        acc[mi][ni] = __builtin_amdgcn_mfma_f32_16x16x32_bf16(af[mi], bfr[ni], acc[mi][ni], 0, 0, 0);
    __syncthreads();
  }
  // ---- epilogue: dump acc+bias to LDS (bf16), then coalesced uint4 RMW ----
  #pragma unroll
  for (int mi = 0; mi < 2; mi++)
    #pragma unroll
    for (int ni = 0; ni < 4; ni++) {
      const int col = wn + ni * 16 + l15;
      const float bv = ld(pe_b2, col, f32);
      #pragma unroll
      for (int r = 0; r < 4; r++) {
        const int row = wm + mi * 16 + quad * 4 + r;
        epi[row * 136 + col] = __bfloat16_as_ushort(f2b(acc[mi][ni][r] + bv));
      }
    }
  __syncthreads();
  uint4* Xu = (uint4*)X;
  #pragma unroll
  for (int j = 0; j < 4; j++) {
    const int i = t + 256 * j;
    const int row = i >> 4, u4 = i & 15;
    uint4 xv = Xu[(size_t)(bm + row) * 16 + u4];
    const uint4 ev = *(const uint4*)(&epi[row * 136 + u4 * 8]);
    const unsigned* xp = reinterpret_cast<const unsigned*>(&xv);
    const unsigned* ep = reinterpret_cast<const unsigned*>(&ev);
    uint4 ov;
    unsigned* op = reinterpret_cast<unsigned*>(&ov);
    #pragma unroll
    for (int c = 0; c < 4; c++) {
      float lo = u2f(xp[c] << 16) + u2f(ep[c] << 16);
      float hi = u2f(xp[c] & 0xFFFF0000u) + u2f(ep[c] & 0xFFFF0000u);
      op[c] = (unsigned)(unsigned short)__bfloat16_as_ushort(f2b(lo))
            | ((unsigned)(unsigned short)__bfloat16_as_ushort(f2b(hi)) << 16);
    }
    Xu[(size_t)(bm + row) * 16 + u4] = ov;
  }
}

extern "C" void kernel_launch(void* const* d_in, const int* in_sizes, int n_in,
                              void* d_out, int out_size, void* d_ws, size_t ws_size,
                              hipStream_t stream) {
  int* flag = (int*)d_ws;
  bf16* ws = (bf16*)d_ws;
  bf16* wswT = ws + 1024;                // 16x128 bf16 (logit W^T), fits in gap < 5760
  bf16* ft   = ws + 5760;                // 6,854,400 (stored as f16)
  bf16* wt1  = ws + 6860160;             // 512x1024
  bf16* wt2  = ws + 7384448;             // 512x512
  bf16* wt3  = ws + 7646592;             // 512x512
  bf16* wt4  = ws + 7908736;             // 128x512
  bf16* pw2t = ws + 7974272;             // 128x256
  bf16* X    = ws + 8007040;             // 40000x1024
  bf16* Ha   = ws + 48967040;            // 40000x512   (ws total ~139 MB)
  bf16* Hb   = X;                        // alias: X dead after layer-1 GEMM
  // sampling scratch aliased onto Ha (dead until layer-1 GEMM writes it)
  float* swG = (float*)Ha;               // 320000x16 fp32 (10.24M be)
  float* uG  = (float*)(ws + 59207040);  // 320000 fp32
  float* vG  = (float*)(ws + 59847040);  // 320000 fp32
  int*   cvG = (int*)(ws + 60487040);    // 320000 int (ends 61127040 < Ha end)

  detect_kernel<<<1, 64, 0, stream>>>(d_in[4], flag);

  tfeat_kernel<<<dim3(210, 6), 256, 0, stream>>>(d_in[0], (__half*)ft, 6720, flag);
  tfeat_kernel<<<dim3(53, 6), 256, 0, stream>>>(d_in[1], (__half*)(ft + 5160960), 1680, flag);
  tfeat_kernel<<<dim3(14, 6), 256, 0, stream>>>(d_in[2], (__half*)(ft + 6451200), 420, flag);
  tfeat_kernel<<<dim3(4, 6), 256, 0, stream>>>(d_in[3], (__half*)(ft + 6773760), 105, flag);
  tw_kernel<<<2048, 256, 0, stream>>>(d_in[13], wt1, 1024, 512, flag);
  tw_kernel<<<1024, 256, 0, stream>>>(d_in[15], wt2, 512, 512, flag);
  tw_kernel<<<1024, 256, 0, stream>>>(d_in[17], wt3, 512, 512, flag);
  tw_kernel<<<256, 256, 0, stream>>>(d_in[19], wt4, 512, 128, flag);
  tw_kernel<<<128, 256, 0, stream>>>(d_in[11], pw2t, 256, 128, flag);
  tw_kernel<<<8, 256, 0, stream>>>(d_in[7], wswT, 128, 16, flag);

  logit_proj_kernel<<<1250, 256, 0, stream>>>(d_in[4], d_in[5], d_in[6], wswT, d_in[8],
                                              swG, uG, vG, cvG, flag);
  gather_kernel<<<80000, 256, 0, stream>>>(swG, uG, vG, cvG, (const __half*)ft, X);
  gemm_pe<<<5000, 256, 0, stream>>>(d_in[5], d_in[9], d_in[10], d_in[12],
                                    pw2t, X, flag);

  const int nbm = 313;  // ceil(40000/128)
  gemm_bt<<<nbm * 4, 256, 0, stream>>>(X,  wt1, d_in[14], Ha, nullptr, 40000, 512, 1024, 1, 0, 4, flag);
  gemm_bt<<<nbm * 4, 256, 0, stream>>>(Ha, wt2, d_in[16], Hb, nullptr, 40000, 512, 512, 1, 0, 4, flag);
  gemm_bt<<<nbm * 4, 256, 0, stream>>>(Hb, wt3, d_in[18], Ha, nullptr, 40000, 512, 512, 1, 0, 4, flag);
  gemm_bt<<<nbm * 1, 256, 0, stream>>>(Ha, wt4, d_in[20], nullptr, (float*)d_out, 40000, 128, 512, 0, 1, 1, flag);
}